// Round 3
// baseline (102.921 us; speedup 1.0000x reference)
//
#include <hip/hip_runtime.h>
#include <hip/hip_bf16.h>

#define N_NODES   50000
#define N_EDGES   625000
#define HF        128
#define K2        256                      // 2*HF
#define MTILE     64                       // edges per tile (v2 fallback)
#define NTILES    ((N_EDGES + MTILE - 1) / MTILE)
#define NT16      ((N_EDGES + 15) / 16)    // 39063 16-edge units
#define P_ELEMS   (NT16 * 16)              // 625008 (padded partials)
#define HB_BYTES  ((size_t)N_NODES * HF * sizeof(short))   // 12,800,000
#define W1F_BYTES ((size_t)32768 * sizeof(short))          // 65,536
#define P_BYTES   ((size_t)P_ELEMS * sizeof(float))        // 2,500,032
#define WS_NEED   (HB_BYTES + W1F_BYTES + 2 * P_BYTES)     // ~17.87 MB
#define V3_BLOCKS 2048

typedef __attribute__((ext_vector_type(8))) short s16x8;
typedef __attribute__((ext_vector_type(4))) float f32x4;

__device__ __forceinline__ short f2bf(float x) {
    unsigned u = __builtin_bit_cast(unsigned, x);
    u += 0x7FFFu + ((u >> 16) & 1u);          // round-to-nearest-even
    return (short)(u >> 16);
}

// ---------------------------------------------------------------------------
// Convert kernel: h (fp32) -> hb (bf16), and W1 -> fragment-ordered bf16.
// w1f index j = ((kt*8 + ntg)*64 + lg*16 + lr), element i:
//   W1[(kt*32 + lg*8 + i)*HF + ntg*16 + lr]
// ---------------------------------------------------------------------------
__global__ void conv_kernel(const float* __restrict__ h,
                            const float* __restrict__ W1,
                            short* __restrict__ hb,
                            short* __restrict__ w1f) {
    int i = blockIdx.x * 256 + threadIdx.x;
    const int n8 = N_NODES * HF / 8;           // 800000
    if (i < n8) {
        f32x4 a = ((const f32x4*)h)[i * 2];
        f32x4 b = ((const f32x4*)h)[i * 2 + 1];
        s16x8 p;
        p[0]=f2bf(a[0]); p[1]=f2bf(a[1]); p[2]=f2bf(a[2]); p[3]=f2bf(a[3]);
        p[4]=f2bf(b[0]); p[5]=f2bf(b[1]); p[6]=f2bf(b[2]); p[7]=f2bf(b[3]);
        ((s16x8*)hb)[i] = p;
    } else {
        int j = i - n8;
        if (j < 4096) {
            const int lr  = j & 15;
            const int lg  = (j >> 4) & 3;
            const int ntg = (j >> 6) & 7;
            const int kt  = j >> 9;
            const int n   = ntg * 16 + lr;
            const int kb  = kt * 32 + lg * 8;
            s16x8 f;
            #pragma unroll
            for (int e = 0; e < 8; ++e) f[e] = f2bf(W1[(size_t)(kb + e) * HF + n]);
            ((s16x8*)w1f)[j] = f;
        }
    }
}

// ---------------------------------------------------------------------------
// Gather one edge's A-fragments straight from hb (per-lane 16B loads).
// k = kt*32 + lg*8 ; src half kt 0..3, dst half kt 4..7
// ---------------------------------------------------------------------------
__device__ __forceinline__ void gatherA(const short* __restrict__ hb,
                                        int sid, int did, int lg, s16x8 (&A)[8]) {
    const s16x8* bs = (const s16x8*)(hb + (size_t)sid * HF);
    const s16x8* bd = (const s16x8*)(hb + (size_t)did * HF);
    A[0] = bs[lg];      A[1] = bs[4 + lg];  A[2] = bs[8 + lg];  A[3] = bs[12 + lg];
    A[4] = bd[lg];      A[5] = bd[4 + lg];  A[6] = bd[8 + lg];  A[7] = bd[12 + lg];
}

// ---------------------------------------------------------------------------
// Main kernel v3: fully decoupled waves. Each wave owns one 16-edge unit
// stream x 64 hidden cols (c = half). No LDS, no barriers. Partial scores
// to p0/p1; combine kernel sums them.
// ---------------------------------------------------------------------------
__device__ __forceinline__ void step_unit_v3(
    int u, int ustride,
    const short* __restrict__ hb,
    const int* __restrict__ src, const int* __restrict__ dst,
    s16x8 (&Acur)[8], s16x8 (&Anext)[8],
    int sidN, int didN,            // ids for u+ustride : gather now
    int& sid2, int& did2,          // out: ids for u+2*ustride
    const s16x8 (&bfrag)[8][4],
    const float (&b1v)[4], const float (&w2v)[4],
    float* __restrict__ pout,
    int lg, int lr)
{
    // issue prefetch gathers for u+ustride (no barrier anywhere: stay in flight)
    gatherA(hb, sidN, didN, lg, Anext);

    // prefetch edge ids for u+2*ustride
    {
        int e = (u + 2 * ustride) * 16 + lr;
        e = e < N_EDGES ? e : N_EDGES - 1;
        sid2 = src[e];
        did2 = dst[e];
    }

    // compute unit: [16 x 256] @ [256 x 64] via 8kt x 4nt MFMA
    f32x4 acc[4];
    #pragma unroll
    for (int nt = 0; nt < 4; ++nt) acc[nt] = (f32x4){0.f, 0.f, 0.f, 0.f};
    #pragma unroll
    for (int kt = 0; kt < 8; ++kt) {
        #pragma unroll
        for (int nt = 0; nt < 4; ++nt)
            acc[nt] = __builtin_amdgcn_mfma_f32_16x16x32_bf16(Acur[kt], bfrag[kt][nt], acc[nt], 0, 0, 0);
    }

    // layer 2 (fp32): relu(acc + b1) . W2, partial over this wave's 64 cols
    // C/D layout: col = lr (n = nt*16+lr), row-in-16 = lg*4 + rr
    float s0[4];
    #pragma unroll
    for (int rr = 0; rr < 4; ++rr) {
        float a = 0.f;
        #pragma unroll
        for (int nt = 0; nt < 4; ++nt) {
            float v = acc[nt][rr] + b1v[nt];
            v = v > 0.f ? v : 0.f;
            a += v * w2v[nt];
        }
        s0[rr] = a;
    }
    // reduce over the 16 lr lanes (masks 1..8 stay within an lg group)
    #pragma unroll
    for (int mask = 1; mask <= 8; mask <<= 1)
        #pragma unroll
        for (int rr = 0; rr < 4; ++rr)
            s0[rr] += __shfl_xor(s0[rr], mask, 64);

    // lanes lr==0 (one per lg) hold rows lg*4 .. lg*4+3 -> one dwordx4 store
    if (lr == 0) {
        f32x4 v;
        v[0] = s0[0]; v[1] = s0[1]; v[2] = s0[2]; v[3] = s0[3];
        *reinterpret_cast<f32x4*>(pout + u * 16 + lg * 4) = v;
    }
}

__global__ __launch_bounds__(256, 2) void mlp_edge_score_v3(
    const short* __restrict__ hb,
    const short* __restrict__ w1f,
    const int*   __restrict__ src,
    const int*   __restrict__ dst,
    const float* __restrict__ b1,
    const float* __restrict__ W2,
    float* __restrict__ p0,
    float* __restrict__ p1)
{
    const int t  = threadIdx.x;
    const int w  = t >> 6;
    const int l  = t & 63;
    const int lg = l >> 4;
    const int lr = l & 15;

    const int gw = blockIdx.x * 4 + w;     // global wave id
    const int c  = gw & 1;                 // col half 0/1
    const int u0 = gw >> 1;                // first 16-edge unit
    const int ustride = gridDim.x * 2;     // units advance per iteration
    float* const pout = c ? p1 : p0;

    // B-fragments: 32 contiguous 16B loads from fragment-ordered w1f
    s16x8 bfrag[8][4];
    #pragma unroll
    for (int kt = 0; kt < 8; ++kt)
        #pragma unroll
        for (int nt = 0; nt < 4; ++nt)
            bfrag[kt][nt] = ((const s16x8*)w1f)[(kt * 8 + c * 4 + nt) * 64 + lg * 16 + lr];

    float b1v[4], w2v[4];
    #pragma unroll
    for (int nt = 0; nt < 4; ++nt) {
        const int n = c * 64 + nt * 16 + lr;
        b1v[nt] = b1[n];
        w2v[nt] = W2[n];
    }

    // prologue: gather for u0; ids for u0+ustride
    s16x8 Aa[8], Ab[8];
    {
        int e = u0 * 16 + lr;
        e = e < N_EDGES ? e : N_EDGES - 1;
        gatherA(hb, src[e], dst[e], lg, Aa);
    }
    int sidA, didA, sidB, didB;
    {
        int e = (u0 + ustride) * 16 + lr;
        e = e < N_EDGES ? e : N_EDGES - 1;
        sidA = src[e]; didA = dst[e];
    }

    for (int u = u0; u < NT16; u += 2 * ustride) {
        step_unit_v3(u, ustride, hb, src, dst, Aa, Ab, sidA, didA, sidB, didB,
                     bfrag, b1v, w2v, pout, lg, lr);
        if (u + ustride < NT16) {
            step_unit_v3(u + ustride, ustride, hb, src, dst, Ab, Aa, sidB, didB, sidA, didA,
                         bfrag, b1v, w2v, pout, lg, lr);
        }
    }
}

// ---------------------------------------------------------------------------
// Combine: out = p0 + p1 + b2
// ---------------------------------------------------------------------------
__global__ void combine_kernel(const float* __restrict__ p0,
                               const float* __restrict__ p1,
                               const float* __restrict__ b2,
                               float* __restrict__ out) {
    int i = blockIdx.x * 256 + threadIdx.x;
    const int n4 = N_EDGES / 4;            // 156250
    if (i < n4) {
        const float b = b2[0];
        f32x4 a = ((const f32x4*)p0)[i];
        f32x4 c = ((const f32x4*)p1)[i];
        f32x4 o;
        o[0] = a[0] + c[0] + b;
        o[1] = a[1] + c[1] + b;
        o[2] = a[2] + c[2] + b;
        o[3] = a[3] + c[3] + b;
        ((f32x4*)out)[i] = o;
    }
}

// ---------------------------------------------------------------------------
// v2 fallback (barrier-coupled, used only if ws too small for v3 layout)
// ---------------------------------------------------------------------------
__global__ void conv_h_kernel(const float* __restrict__ h, short* __restrict__ hb) {
    int i = blockIdx.x * blockDim.x + threadIdx.x;
    const int n8 = N_NODES * HF / 8;
    if (i < n8) {
        f32x4 a = ((const f32x4*)h)[i * 2];
        f32x4 b = ((const f32x4*)h)[i * 2 + 1];
        s16x8 p;
        p[0]=f2bf(a[0]); p[1]=f2bf(a[1]); p[2]=f2bf(a[2]); p[3]=f2bf(a[3]);
        p[4]=f2bf(b[0]); p[5]=f2bf(b[1]); p[6]=f2bf(b[2]); p[7]=f2bf(b[3]);
        ((s16x8*)hb)[i] = p;
    }
}

__device__ __forceinline__ void step_tile_v2(
    int tile, int g,
    const short* __restrict__ hb,
    const int* __restrict__ src, const int* __restrict__ dst,
    s16x8 (&Acur)[8], s16x8 (&Anext)[8],
    int sidg, int didg, int& sid2, int& did2,
    const s16x8 (&bfrag)[8][4],
    const float (&b1v)[4], const float (&w2v)[4], float b2v,
    float* __restrict__ out,
    float (&lds_p)[2][2][MTILE], int pp,
    int t, int r, int c, int lg, int lr, int myrow)
{
    gatherA(hb, sidg, didg, lg, Anext);
    {
        int e = (tile + 2 * g) * MTILE + myrow;
        e = e < N_EDGES ? e : N_EDGES - 1;
        sid2 = src[e]; did2 = dst[e];
    }
    f32x4 acc[4];
    #pragma unroll
    for (int nt = 0; nt < 4; ++nt) acc[nt] = (f32x4){0.f, 0.f, 0.f, 0.f};
    #pragma unroll
    for (int kt = 0; kt < 8; ++kt)
        #pragma unroll
        for (int nt = 0; nt < 4; ++nt)
            acc[nt] = __builtin_amdgcn_mfma_f32_16x16x32_bf16(Acur[kt], bfrag[kt][nt], acc[nt], 0, 0, 0);

    float s0[4];
    #pragma unroll
    for (int rr = 0; rr < 4; ++rr) {
        float a = 0.f;
        #pragma unroll
        for (int nt = 0; nt < 4; ++nt) {
            float v = acc[nt][rr] + b1v[nt];
            v = v > 0.f ? v : 0.f;
            a += v * w2v[nt];
        }
        s0[rr] = a;
    }
    #pragma unroll
    for (int mask = 1; mask <= 8; mask <<= 1)
        #pragma unroll
        for (int rr = 0; rr < 4; ++rr)
            s0[rr] += __shfl_xor(s0[rr], mask, 64);

    if (lr == 0) {
        #pragma unroll
        for (int rr = 0; rr < 4; ++rr)
            lds_p[pp][c][r * 16 + lg * 4 + rr] = s0[rr];
    }
    asm volatile("s_waitcnt lgkmcnt(0)" ::: "memory");
    __builtin_amdgcn_s_barrier();
    asm volatile("" ::: "memory");

    if (t < MTILE) {
        int e = tile * MTILE + t;
        if (e < N_EDGES)
            out[e] = lds_p[pp][0][t] + lds_p[pp][1][t] + b2v;
    }
}

__global__ __launch_bounds__(512, 2) void mlp_edge_score_v2(
    const short* __restrict__ hb,
    const int*   __restrict__ src,
    const int*   __restrict__ dst,
    const float* __restrict__ W1,
    const float* __restrict__ b1,
    const float* __restrict__ W2,
    const float* __restrict__ b2,
    float* __restrict__ out)
{
    __shared__ float lds_p[2][2][MTILE];

    const int t  = threadIdx.x;
    const int w  = t >> 6;
    const int l  = t & 63;
    const int r  = w >> 1;
    const int c  = w & 1;
    const int lg = l >> 4;
    const int lr = l & 15;
    const int myrow = r * 16 + lr;

    s16x8 bfrag[8][4];
    #pragma unroll
    for (int kt = 0; kt < 8; ++kt)
        #pragma unroll
        for (int nt = 0; nt < 4; ++nt) {
            const int n  = c * 64 + nt * 16 + lr;
            const int kb = kt * 32 + lg * 8;
            s16x8 f;
            #pragma unroll
            for (int i = 0; i < 8; ++i) f[i] = f2bf(W1[(size_t)(kb + i) * HF + n]);
            bfrag[kt][nt] = f;
        }
    float b1v[4], w2v[4];
    #pragma unroll
    for (int nt = 0; nt < 4; ++nt) {
        const int n = c * 64 + nt * 16 + lr;
        b1v[nt] = b1[n];
        w2v[nt] = W2[n];
    }
    const float b2v = b2[0];

    const int g = gridDim.x;
    const int tile0 = blockIdx.x;

    s16x8 Aa[8], Ab[8];
    {
        int e = tile0 * MTILE + myrow;
        e = e < N_EDGES ? e : N_EDGES - 1;
        gatherA(hb, src[e], dst[e], lg, Aa);
    }
    int sidA, didA, sidB, didB;
    {
        int e = (tile0 + g) * MTILE + myrow;
        e = e < N_EDGES ? e : N_EDGES - 1;
        sidA = src[e]; didA = dst[e];
    }

    int pp = 0;
    for (int tile = tile0; tile < NTILES; tile += 2 * g) {
        step_tile_v2(tile, g, hb, src, dst, Aa, Ab, sidA, didA, sidB, didB,
                     bfrag, b1v, w2v, b2v, out, lds_p, pp, t, r, c, lg, lr, myrow);
        pp ^= 1;
        if (tile + g < NTILES) {
            step_tile_v2(tile + g, g, hb, src, dst, Ab, Aa, sidB, didB, sidA, didA,
                         bfrag, b1v, w2v, b2v, out, lds_p, pp, t, r, c, lg, lr, myrow);
            pp ^= 1;
        }
    }
}

extern "C" void kernel_launch(void* const* d_in, const int* in_sizes, int n_in,
                              void* d_out, int out_size, void* d_ws, size_t ws_size,
                              hipStream_t stream) {
    const float* h   = (const float*)d_in[0];
    const int*   src = (const int*)  d_in[1];
    const int*   dst = (const int*)  d_in[2];
    const float* W1  = (const float*)d_in[3];
    const float* b1  = (const float*)d_in[4];
    const float* W2  = (const float*)d_in[5];
    const float* b2  = (const float*)d_in[6];
    float* out = (float*)d_out;

    if (ws_size >= WS_NEED) {
        char* ws = (char*)d_ws;
        short* hb  = (short*)ws;
        short* w1f = (short*)(ws + HB_BYTES);
        float* p0  = (float*)(ws + HB_BYTES + W1F_BYTES);
        float* p1  = (float*)(ws + HB_BYTES + W1F_BYTES + P_BYTES);

        const int nconv = N_NODES * HF / 8 + 4096;
        conv_kernel<<<(nconv + 255) / 256, 256, 0, stream>>>(h, W1, hb, w1f);
        mlp_edge_score_v3<<<V3_BLOCKS, 256, 0, stream>>>(hb, w1f, src, dst, b1, W2, p0, p1);
        combine_kernel<<<(N_EDGES / 4 + 255) / 256, 256, 0, stream>>>(p0, p1, b2, out);
    } else {
        short* hb = (short*)d_ws;
        const int n8 = N_NODES * HF / 8;
        conv_h_kernel<<<(n8 + 255) / 256, 256, 0, stream>>>(h, hb);
        mlp_edge_score_v2<<<256, 512, 0, stream>>>(hb, src, dst, W1, b1, W2, b2, out);
    }
}

// Round 4
// 74.961 us; speedup vs baseline: 1.3730x; 1.3730x over previous
//
#include <hip/hip_runtime.h>
#include <hip/hip_bf16.h>

#define N_NODES   50000
#define N_EDGES   625000
#define HF        128
#define MTILE     64
#define NTILES    ((N_EDGES + MTILE - 1) / MTILE)
#define HB_BYTES  ((size_t)N_NODES * HF * sizeof(short))     // 12,800,000 (v2 fallback)
#define W1F_BYTES ((size_t)4096 * 16)                        // 65,536
#define UV_BYTES  ((size_t)N_NODES * 256 * sizeof(short))    // 25,600,000
#define WS_NEED   (W1F_BYTES + UV_BYTES)                     // 25,665,536

typedef __attribute__((ext_vector_type(8))) short s16x8;
typedef __attribute__((ext_vector_type(4))) float f32x4;

__device__ __forceinline__ short f2bf(float x) {
    unsigned u = __builtin_bit_cast(unsigned, x);
    u += 0x7FFFu + ((u >> 16) & 1u);          // round-to-nearest-even
    return (short)(u >> 16);
}
__device__ __forceinline__ float bf2f(short s) {
    return __builtin_bit_cast(float, ((unsigned)(unsigned short)s) << 16);
}

// ---------------------------------------------------------------------------
// W -> fragment-ordered bf16. Combined B = [W1[0:128,:] | W1[128:256,:]],
// K=128 (h feature), N=256 (U cols 0..127, V cols 128..255).
// w1f index j = ((kt*16 + ntg)*64 + lg*16 + lr), element i:
//   k = kt*32 + lg*8 + i ; n2 = ntg*16 + lr
//   B[k][n2] = n2<128 ? W1[k][n2] : W1[k+128][n2-128]
// ---------------------------------------------------------------------------
__global__ void conv_w_kernel(const float* __restrict__ W1, short* __restrict__ w1f) {
    int j = blockIdx.x * 256 + threadIdx.x;
    if (j < 4096) {
        const int lr  = j & 15;
        const int lg  = (j >> 4) & 3;
        const int ntg = (j >> 6) & 15;
        const int kt  = j >> 10;
        const int n2  = ntg * 16 + lr;
        const int kb  = kt * 32 + lg * 8;
        const float* wp = (n2 < 128) ? (W1 + (size_t)kb * 128 + n2)
                                     : (W1 + (size_t)(kb + 128) * 128 + (n2 - 128));
        s16x8 f;
        #pragma unroll
        for (int i = 0; i < 8; ++i) f[i] = f2bf(wp[(size_t)i * 128]);
        ((s16x8*)w1f)[j] = f;
    }
}

// ---------------------------------------------------------------------------
// UV GEMM: [50000 x 128] @ [128 x 256] -> UV bf16 [50000][256], +0.5*b1 fold.
// Block = 4 waves: (rgrp 0/1) x (chl 0/1); block tile 32 rows x 128 cols.
// grid = ceil(50000/32) * 2 = 3126 blocks.
// ---------------------------------------------------------------------------
__global__ __launch_bounds__(256, 4) void uv_gemm_kernel(
    const float* __restrict__ h,
    const short* __restrict__ w1f,
    const float* __restrict__ b1,
    short* __restrict__ UV)
{
    const int t  = threadIdx.x;
    const int w  = t >> 6;
    const int l  = t & 63;
    const int lg = l >> 4;
    const int lr = l & 15;

    const int mblk = blockIdx.x >> 1;
    const int cb   = blockIdx.x & 1;
    const int rgrp = w >> 1;
    const int chl  = w & 1;
    const int R = mblk * 32 + rgrp * 16;
    const int C = cb * 128 + chl * 64;

    // B fragments (16 x s16x8 = 64 VGPR)
    s16x8 bfrag[4][4];
    #pragma unroll
    for (int kt = 0; kt < 4; ++kt)
        #pragma unroll
        for (int nt = 0; nt < 4; ++nt) {
            const int ntg = cb * 8 + chl * 4 + nt;
            bfrag[kt][nt] = ((const s16x8*)w1f)[(kt * 16 + ntg) * 64 + lg * 16 + lr];
        }

    // A fragments: row = R+lr, k = kt*32 + lg*8 + i (fp32 -> bf16 inline)
    int row = R + lr; if (row > N_NODES - 1) row = N_NODES - 1;
    const float* hp = h + (size_t)row * HF + lg * 8;
    s16x8 afr[4];
    #pragma unroll
    for (int kt = 0; kt < 4; ++kt) {
        f32x4 a = *reinterpret_cast<const f32x4*>(hp + kt * 32);
        f32x4 b = *reinterpret_cast<const f32x4*>(hp + kt * 32 + 4);
        s16x8 p;
        p[0]=f2bf(a[0]); p[1]=f2bf(a[1]); p[2]=f2bf(a[2]); p[3]=f2bf(a[3]);
        p[4]=f2bf(b[0]); p[5]=f2bf(b[1]); p[6]=f2bf(b[2]); p[7]=f2bf(b[3]);
        afr[kt] = p;
    }

    f32x4 acc[4];
    #pragma unroll
    for (int nt = 0; nt < 4; ++nt) acc[nt] = (f32x4){0.f, 0.f, 0.f, 0.f};
    #pragma unroll
    for (int kt = 0; kt < 4; ++kt)
        #pragma unroll
        for (int nt = 0; nt < 4; ++nt)
            acc[nt] = __builtin_amdgcn_mfma_f32_16x16x32_bf16(afr[kt], bfrag[kt][nt], acc[nt], 0, 0, 0);

    // epilogue: +0.5*b1[dim], store bf16. C/D: col = lr, row = lg*4 + rr.
    #pragma unroll
    for (int nt = 0; nt < 4; ++nt) {
        const int col = C + nt * 16 + lr;
        const float bh = 0.5f * b1[col & 127];
        #pragma unroll
        for (int rr = 0; rr < 4; ++rr) {
            const int orow = R + lg * 4 + rr;
            if (orow < N_NODES)
                UV[(size_t)orow * 256 + col] = f2bf(acc[nt][rr] + bh);
        }
    }
}

// ---------------------------------------------------------------------------
// Edge combine: out[e] = sum_d relu(U[src[e]][d] + V[dst[e]][d]) * W2[d] + b2
// 8 lanes/edge x 16 dims/lane; 16 edges per wave-iteration (2 batches of 8).
// ---------------------------------------------------------------------------
__device__ __forceinline__ float dotrelu8(s16x8 u, s16x8 v, const float* w2v, int off) {
    float a = 0.f;
    #pragma unroll
    for (int j = 0; j < 8; ++j) {
        float s = bf2f(u[j]) + bf2f(v[j]);
        s = s > 0.f ? s : 0.f;
        a += s * w2v[off + j];
    }
    return a;
}

__global__ __launch_bounds__(256) void edge_combine_kernel(
    const short* __restrict__ UV,
    const int*   __restrict__ src,
    const int*   __restrict__ dst,
    const float* __restrict__ W2,
    const float* __restrict__ b2,
    float* __restrict__ out)
{
    const int t  = threadIdx.x;
    const int w  = t >> 6;
    const int l  = t & 63;
    const int eg = l >> 3;         // edge-in-batch 0..7
    const int dg = l & 7;          // dim group 0..7
    const int dl = dg * 16;        // dim base

    float w2v[16];
    #pragma unroll
    for (int j = 0; j < 16; ++j) w2v[j] = W2[dl + j];
    const float b2v = b2[0];

    const int gw = blockIdx.x * 4 + w;
    const int nw = gridDim.x * 4;

    for (int base = gw * 16; base < N_EDGES; base += nw * 16) {
        const int ei0 = base + eg;
        const int ei1 = base + 8 + eg;
        const int c0 = ei0 < N_EDGES ? ei0 : N_EDGES - 1;
        const int c1 = ei1 < N_EDGES ? ei1 : N_EDGES - 1;
        // ids (two batches issued together)
        const int s0 = src[c0], d0 = dst[c0];
        const int s1 = src[c1], d1 = dst[c1];
        // gathers (8 x 16B issued together)
        const s16x8* u0p = (const s16x8*)(UV + (size_t)s0 * 256 + dl);
        const s16x8* v0p = (const s16x8*)(UV + (size_t)d0 * 256 + 128 + dl);
        const s16x8* u1p = (const s16x8*)(UV + (size_t)s1 * 256 + dl);
        const s16x8* v1p = (const s16x8*)(UV + (size_t)d1 * 256 + 128 + dl);
        s16x8 ua = u0p[0], ub = u0p[1], va = v0p[0], vb = v0p[1];
        s16x8 uc = u1p[0], ud = u1p[1], vc = v1p[0], vd = v1p[1];

        float a0 = dotrelu8(ua, va, w2v, 0) + dotrelu8(ub, vb, w2v, 8);
        float a1 = dotrelu8(uc, vc, w2v, 0) + dotrelu8(ud, vd, w2v, 8);

        #pragma unroll
        for (int m = 1; m <= 4; m <<= 1) {
            a0 += __shfl_xor(a0, m, 64);
            a1 += __shfl_xor(a1, m, 64);
        }
        if (dg == 0) {
            if (ei0 < N_EDGES) out[ei0] = a0 + b2v;
            if (ei1 < N_EDGES) out[ei1] = a1 + b2v;
        }
    }
}

// ---------------------------------------------------------------------------
// v2 fallback (used only if ws too small): bf16 h + direct-gather MFMA
// ---------------------------------------------------------------------------
__global__ void conv_h_kernel(const float* __restrict__ h, short* __restrict__ hb) {
    int i = blockIdx.x * blockDim.x + threadIdx.x;
    const int n8 = N_NODES * HF / 8;
    if (i < n8) {
        f32x4 a = ((const f32x4*)h)[i * 2];
        f32x4 b = ((const f32x4*)h)[i * 2 + 1];
        s16x8 p;
        p[0]=f2bf(a[0]); p[1]=f2bf(a[1]); p[2]=f2bf(a[2]); p[3]=f2bf(a[3]);
        p[4]=f2bf(b[0]); p[5]=f2bf(b[1]); p[6]=f2bf(b[2]); p[7]=f2bf(b[3]);
        ((s16x8*)hb)[i] = p;
    }
}

__device__ __forceinline__ void gatherA(const short* __restrict__ hb,
                                        int sid, int did, int lg, s16x8 (&A)[8]) {
    const s16x8* bs = (const s16x8*)(hb + (size_t)sid * HF);
    const s16x8* bd = (const s16x8*)(hb + (size_t)did * HF);
    A[0] = bs[lg];      A[1] = bs[4 + lg];  A[2] = bs[8 + lg];  A[3] = bs[12 + lg];
    A[4] = bd[lg];      A[5] = bd[4 + lg];  A[6] = bd[8 + lg];  A[7] = bd[12 + lg];
}

__device__ __forceinline__ void step_tile_v2(
    int tile, int g,
    const short* __restrict__ hb,
    const int* __restrict__ src, const int* __restrict__ dst,
    s16x8 (&Acur)[8], s16x8 (&Anext)[8],
    int sidg, int didg, int& sid2, int& did2,
    const s16x8 (&bfrag)[8][4],
    const float (&b1v)[4], const float (&w2v)[4], float b2v,
    float* __restrict__ out,
    float (&lds_p)[2][2][MTILE], int pp,
    int t, int r, int c, int lg, int lr, int myrow)
{
    gatherA(hb, sidg, didg, lg, Anext);
    {
        int e = (tile + 2 * g) * MTILE + myrow;
        e = e < N_EDGES ? e : N_EDGES - 1;
        sid2 = src[e]; did2 = dst[e];
    }
    f32x4 acc[4];
    #pragma unroll
    for (int nt = 0; nt < 4; ++nt) acc[nt] = (f32x4){0.f, 0.f, 0.f, 0.f};
    #pragma unroll
    for (int kt = 0; kt < 8; ++kt)
        #pragma unroll
        for (int nt = 0; nt < 4; ++nt)
            acc[nt] = __builtin_amdgcn_mfma_f32_16x16x32_bf16(Acur[kt], bfrag[kt][nt], acc[nt], 0, 0, 0);

    float s0[4];
    #pragma unroll
    for (int rr = 0; rr < 4; ++rr) {
        float a = 0.f;
        #pragma unroll
        for (int nt = 0; nt < 4; ++nt) {
            float v = acc[nt][rr] + b1v[nt];
            v = v > 0.f ? v : 0.f;
            a += v * w2v[nt];
        }
        s0[rr] = a;
    }
    #pragma unroll
    for (int mask = 1; mask <= 8; mask <<= 1)
        #pragma unroll
        for (int rr = 0; rr < 4; ++rr)
            s0[rr] += __shfl_xor(s0[rr], mask, 64);

    if (lr == 0) {
        #pragma unroll
        for (int rr = 0; rr < 4; ++rr)
            lds_p[pp][c][r * 16 + lg * 4 + rr] = s0[rr];
    }
    asm volatile("s_waitcnt lgkmcnt(0)" ::: "memory");
    __builtin_amdgcn_s_barrier();
    asm volatile("" ::: "memory");

    if (t < MTILE) {
        int e = tile * MTILE + t;
        if (e < N_EDGES)
            out[e] = lds_p[pp][0][t] + lds_p[pp][1][t] + b2v;
    }
}

__global__ __launch_bounds__(512, 2) void mlp_edge_score_v2(
    const short* __restrict__ hb,
    const int*   __restrict__ src,
    const int*   __restrict__ dst,
    const float* __restrict__ W1,
    const float* __restrict__ b1,
    const float* __restrict__ W2,
    const float* __restrict__ b2,
    float* __restrict__ out)
{
    __shared__ float lds_p[2][2][MTILE];

    const int t  = threadIdx.x;
    const int w  = t >> 6;
    const int l  = t & 63;
    const int r  = w >> 1;
    const int c  = w & 1;
    const int lg = l >> 4;
    const int lr = l & 15;
    const int myrow = r * 16 + lr;

    s16x8 bfrag[8][4];
    #pragma unroll
    for (int kt = 0; kt < 8; ++kt)
        #pragma unroll
        for (int nt = 0; nt < 4; ++nt) {
            const int n  = c * 64 + nt * 16 + lr;
            const int kb = kt * 32 + lg * 8;
            s16x8 f;
            #pragma unroll
            for (int i = 0; i < 8; ++i) f[i] = f2bf(W1[(size_t)(kb + i) * HF + n]);
            bfrag[kt][nt] = f;
        }
    float b1v[4], w2v[4];
    #pragma unroll
    for (int nt = 0; nt < 4; ++nt) {
        const int n = c * 64 + nt * 16 + lr;
        b1v[nt] = b1[n];
        w2v[nt] = W2[n];
    }
    const float b2v = b2[0];

    const int g = gridDim.x;
    const int tile0 = blockIdx.x;

    s16x8 Aa[8], Ab[8];
    {
        int e = tile0 * MTILE + myrow;
        e = e < N_EDGES ? e : N_EDGES - 1;
        gatherA(hb, src[e], dst[e], lg, Aa);
    }
    int sidA, didA, sidB, didB;
    {
        int e = (tile0 + g) * MTILE + myrow;
        e = e < N_EDGES ? e : N_EDGES - 1;
        sidA = src[e]; didA = dst[e];
    }

    int pp = 0;
    for (int tile = tile0; tile < NTILES; tile += 2 * g) {
        step_tile_v2(tile, g, hb, src, dst, Aa, Ab, sidA, didA, sidB, didB,
                     bfrag, b1v, w2v, b2v, out, lds_p, pp, t, r, c, lg, lr, myrow);
        pp ^= 1;
        if (tile + g < NTILES) {
            step_tile_v2(tile + g, g, hb, src, dst, Ab, Aa, sidB, didB, sidA, didA,
                         bfrag, b1v, w2v, b2v, out, lds_p, pp, t, r, c, lg, lr, myrow);
            pp ^= 1;
        }
    }
}

extern "C" void kernel_launch(void* const* d_in, const int* in_sizes, int n_in,
                              void* d_out, int out_size, void* d_ws, size_t ws_size,
                              hipStream_t stream) {
    const float* h   = (const float*)d_in[0];
    const int*   src = (const int*)  d_in[1];
    const int*   dst = (const int*)  d_in[2];
    const float* W1  = (const float*)d_in[3];
    const float* b1  = (const float*)d_in[4];
    const float* W2  = (const float*)d_in[5];
    const float* b2  = (const float*)d_in[6];
    float* out = (float*)d_out;

    if (ws_size >= WS_NEED) {
        char* ws = (char*)d_ws;
        short* w1f = (short*)ws;
        short* UV  = (short*)(ws + W1F_BYTES);

        conv_w_kernel<<<16, 256, 0, stream>>>(W1, w1f);
        uv_gemm_kernel<<<((N_NODES + 31) / 32) * 2, 256, 0, stream>>>(h, w1f, b1, UV);
        edge_combine_kernel<<<2048, 256, 0, stream>>>(UV, src, dst, W2, b2, out);
    } else {
        short* hb = (short*)d_ws;
        const int n8 = N_NODES * HF / 8;
        conv_h_kernel<<<(n8 + 255) / 256, 256, 0, stream>>>(h, hb);
        mlp_edge_score_v2<<<256, 512, 0, stream>>>(hb, src, dst, W1, b1, W2, b2, out);
    }
}

// Round 5
// 74.062 us; speedup vs baseline: 1.3897x; 1.0121x over previous
//
#include <hip/hip_runtime.h>
#include <hip/hip_bf16.h>

#define N_NODES   50000
#define N_EDGES   625000
#define HF        128
#define MTILE     64
#define NTILES    ((N_EDGES + MTILE - 1) / MTILE)
#define HB_BYTES  ((size_t)N_NODES * HF * sizeof(short))     // v2 fallback
#define W1F_BYTES ((size_t)4096 * 16)                        // 65,536
#define UV_BYTES  ((size_t)N_NODES * 256 * sizeof(short))    // 25,600,000
#define WS_NEED   (W1F_BYTES + UV_BYTES)

typedef __attribute__((ext_vector_type(8))) short s16x8;
typedef __attribute__((ext_vector_type(4))) float f32x4;

__device__ __forceinline__ short f2bf(float x) {
    unsigned u = __builtin_bit_cast(unsigned, x);
    u += 0x7FFFu + ((u >> 16) & 1u);          // round-to-nearest-even
    return (short)(u >> 16);
}
__device__ __forceinline__ float bf2f(short s) {
    return __builtin_bit_cast(float, ((unsigned)(unsigned short)s) << 16);
}

// ---------------------------------------------------------------------------
// W -> fragment-ordered bf16. Combined B = [W1[0:128,:] | W1[128:256,:]],
// K=128, N=256 (U cols 0..127 from W1 top half, V cols 128..255 bottom half).
// w1f index j = ((kt*16 + ntg)*64 + lg*16 + lr), element i:
//   k = kt*32 + lg*8 + i ; n2 = ntg*16 + lr
// ---------------------------------------------------------------------------
__global__ void conv_w_kernel(const float* __restrict__ W1, short* __restrict__ w1f) {
    int j = blockIdx.x * 256 + threadIdx.x;
    if (j < 4096) {
        const int lr  = j & 15;
        const int lg  = (j >> 4) & 3;
        const int ntg = (j >> 6) & 15;
        const int kt  = j >> 10;
        const int n2  = ntg * 16 + lr;
        const int kb  = kt * 32 + lg * 8;
        const float* wp = (n2 < 128) ? (W1 + (size_t)kb * 128 + n2)
                                     : (W1 + (size_t)(kb + 128) * 128 + (n2 - 128));
        s16x8 f;
        #pragma unroll
        for (int i = 0; i < 8; ++i) f[i] = f2bf(wp[(size_t)i * 128]);
        ((s16x8*)w1f)[j] = f;
    }
}

// ---------------------------------------------------------------------------
// UV GEMM v2: [50000 x 128] @ [128 x 256] -> UV bf16, +0.5*b1 fold.
// One 512-thread block per 32-row tile (8 waves = 2 rgrp x 4 chl): h read
// once per tile; epilogue transposed through padded LDS -> coalesced 16B
// stores (round-4 epilogue was 16 scattered 2B stores/lane = the 28us sin).
// ---------------------------------------------------------------------------
#define CPAD 272   // LDS row stride in shorts: 544B = 136 dw = +8 banks/row
__global__ __launch_bounds__(512) void uv_gemm2_kernel(
    const float* __restrict__ h,
    const short* __restrict__ w1f,
    const float* __restrict__ b1,
    short* __restrict__ UV)
{
    __shared__ short ldsC[32 * CPAD];   // ~17 KB

    const int t  = threadIdx.x;
    const int w  = t >> 6;
    const int l  = t & 63;
    const int lg = l >> 4;
    const int lr = l & 15;
    const int rgrp = w >> 2;            // 0/1 : rows  rgrp*16..+15
    const int chl  = w & 3;             // 0..3: cols  chl*64..+63
    const int R0 = blockIdx.x * 32;

    // B fragments (64 VGPR)
    s16x8 bfrag[4][4];
    #pragma unroll
    for (int kt = 0; kt < 4; ++kt)
        #pragma unroll
        for (int nt = 0; nt < 4; ++nt)
            bfrag[kt][nt] = ((const s16x8*)w1f)[(kt * 16 + chl * 4 + nt) * 64 + lg * 16 + lr];

    float b1v[4];
    #pragma unroll
    for (int nt = 0; nt < 4; ++nt)
        b1v[nt] = 0.5f * b1[(chl * 64 + nt * 16 + lr) & 127];

    // A fragments: row = R0 + rgrp*16 + lr, k = kt*32 + lg*8 + i
    int arow = R0 + rgrp * 16 + lr; if (arow > N_NODES - 1) arow = N_NODES - 1;
    const float* hp = h + (size_t)arow * HF + lg * 8;
    s16x8 afr[4];
    #pragma unroll
    for (int kt = 0; kt < 4; ++kt) {
        f32x4 a = *reinterpret_cast<const f32x4*>(hp + kt * 32);
        f32x4 b = *reinterpret_cast<const f32x4*>(hp + kt * 32 + 4);
        s16x8 p;
        p[0]=f2bf(a[0]); p[1]=f2bf(a[1]); p[2]=f2bf(a[2]); p[3]=f2bf(a[3]);
        p[4]=f2bf(b[0]); p[5]=f2bf(b[1]); p[6]=f2bf(b[2]); p[7]=f2bf(b[3]);
        afr[kt] = p;
    }

    f32x4 acc[4];
    #pragma unroll
    for (int nt = 0; nt < 4; ++nt) acc[nt] = (f32x4){0.f, 0.f, 0.f, 0.f};
    #pragma unroll
    for (int kt = 0; kt < 4; ++kt)
        #pragma unroll
        for (int nt = 0; nt < 4; ++nt)
            acc[nt] = __builtin_amdgcn_mfma_f32_16x16x32_bf16(afr[kt], bfrag[kt][nt], acc[nt], 0, 0, 0);

    // epilogue: acc -> LDS (bf16, +bias). C/D: col = lr, row = lg*4 + rr.
    #pragma unroll
    for (int nt = 0; nt < 4; ++nt) {
        const int col = chl * 64 + nt * 16 + lr;
        #pragma unroll
        for (int rr = 0; rr < 4; ++rr)
            ldsC[(rgrp * 16 + lg * 4 + rr) * CPAD + col] = f2bf(acc[nt][rr] + b1v[nt]);
    }
    __syncthreads();

    // coalesced store: 32 rows x 32 chunks x 16B, 2 rounds of 512 threads
    #pragma unroll
    for (int i = 0; i < 2; ++i) {
        const int idx = t + i * 512;
        const int r2 = idx >> 5, ch = idx & 31;
        const int grow = R0 + r2;
        if (grow < N_NODES) {
            s16x8 vv = *reinterpret_cast<const s16x8*>(&ldsC[r2 * CPAD + ch * 8]);
            *reinterpret_cast<s16x8*>(&UV[(size_t)grow * 256 + ch * 8]) = vv;
        }
    }
}

// ---------------------------------------------------------------------------
// Edge combine v2: out[e] = sum_d relu(U[src][d] + V[dst][d]) * W2[d] + b2
// 8 lanes/edge x 16 dims/lane; 32 edges per wave-iter (4 sub-batches of 8);
// ids deduped via one coalesced load + shfl broadcast; next-iter ids
// prefetched under compute.
// ---------------------------------------------------------------------------
__device__ __forceinline__ float dotrelu8(s16x8 u, s16x8 v, const float* w2v, int off) {
    float a = 0.f;
    #pragma unroll
    for (int j = 0; j < 8; ++j) {
        float s = bf2f(u[j]) + bf2f(v[j]);
        s = s > 0.f ? s : 0.f;
        a += s * w2v[off + j];
    }
    return a;
}

__global__ __launch_bounds__(256) void edge_combine2_kernel(
    const short* __restrict__ UV,
    const int*   __restrict__ src,
    const int*   __restrict__ dst,
    const float* __restrict__ W2,
    const float* __restrict__ b2,
    float* __restrict__ out)
{
    const int t  = threadIdx.x;
    const int w  = t >> 6;
    const int l  = t & 63;
    const int eg = l >> 3;         // edge-in-sub-batch 0..7
    const int dg = l & 7;          // dim group 0..7
    const int dl = dg * 16;        // dim base

    float w2v[16];
    #pragma unroll
    for (int j = 0; j < 16; ++j) w2v[j] = W2[dl + j];
    const float b2v = b2[0];

    const int gw = blockIdx.x * 4 + w;
    const int stride = gridDim.x * 4 * 32;

    int base = gw * 32;
    // ids for first iter: lane j<32 -> src[base+j], lane j>=32 -> dst[base+j-32]
    {
        int jj = base + (l & 31); if (jj > N_EDGES - 1) jj = N_EDGES - 1;
        // (guard for gw*32 >= N_EDGES handled by loop condition; load is clamped)
    }
    int jj0 = base + (l & 31); if (jj0 > N_EDGES - 1) jj0 = N_EDGES - 1;
    if (jj0 < 0) jj0 = 0;
    int ids = (l < 32) ? src[jj0] : dst[jj0];

    for (; base < N_EDGES; base += stride) {
        int s[4], d[4];
        #pragma unroll
        for (int k = 0; k < 4; ++k) {
            s[k] = __shfl(ids, k * 8 + eg, 64);
            d[k] = __shfl(ids, 32 + k * 8 + eg, 64);
        }

        // issue all 16 gathers before any consume (16 x 16B in flight)
        s16x8 u0[4], u1[4], v0[4], v1[4];
        #pragma unroll
        for (int k = 0; k < 4; ++k) {
            const s16x8* up = (const s16x8*)(UV + (size_t)s[k] * 256 + dl);
            const s16x8* vp = (const s16x8*)(UV + (size_t)d[k] * 256 + 128 + dl);
            u0[k] = up[0]; u1[k] = up[1];
            v0[k] = vp[0]; v1[k] = vp[1];
        }

        // prefetch next iteration's ids under the gather latency
        const int nb = base + stride;
        if (nb < N_EDGES) {
            int j2 = nb + (l & 31); if (j2 > N_EDGES - 1) j2 = N_EDGES - 1;
            ids = (l < 32) ? src[j2] : dst[j2];
        }

        float a[4];
        #pragma unroll
        for (int k = 0; k < 4; ++k)
            a[k] = dotrelu8(u0[k], v0[k], w2v, 0) + dotrelu8(u1[k], v1[k], w2v, 8);

        #pragma unroll
        for (int m = 1; m <= 4; m <<= 1)
            #pragma unroll
            for (int k = 0; k < 4; ++k)
                a[k] += __shfl_xor(a[k], m, 64);

        if (dg == 0) {
            #pragma unroll
            for (int k = 0; k < 4; ++k) {
                const int ei = base + k * 8 + eg;
                if (ei < N_EDGES) __builtin_nontemporal_store(a[k] + b2v, &out[ei]);
            }
        }
    }
}

// ---------------------------------------------------------------------------
// v2 fallback (only if ws too small): bf16 h + direct-gather MFMA
// ---------------------------------------------------------------------------
__global__ void conv_h_kernel(const float* __restrict__ h, short* __restrict__ hb) {
    int i = blockIdx.x * blockDim.x + threadIdx.x;
    const int n8 = N_NODES * HF / 8;
    if (i < n8) {
        f32x4 a = ((const f32x4*)h)[i * 2];
        f32x4 b = ((const f32x4*)h)[i * 2 + 1];
        s16x8 p;
        p[0]=f2bf(a[0]); p[1]=f2bf(a[1]); p[2]=f2bf(a[2]); p[3]=f2bf(a[3]);
        p[4]=f2bf(b[0]); p[5]=f2bf(b[1]); p[6]=f2bf(b[2]); p[7]=f2bf(b[3]);
        ((s16x8*)hb)[i] = p;
    }
}

__device__ __forceinline__ void gatherA(const short* __restrict__ hb,
                                        int sid, int did, int lg, s16x8 (&A)[8]) {
    const s16x8* bs = (const s16x8*)(hb + (size_t)sid * HF);
    const s16x8* bd = (const s16x8*)(hb + (size_t)did * HF);
    A[0] = bs[lg];      A[1] = bs[4 + lg];  A[2] = bs[8 + lg];  A[3] = bs[12 + lg];
    A[4] = bd[lg];      A[5] = bd[4 + lg];  A[6] = bd[8 + lg];  A[7] = bd[12 + lg];
}

__device__ __forceinline__ void step_tile_v2(
    int tile, int g,
    const short* __restrict__ hb,
    const int* __restrict__ src, const int* __restrict__ dst,
    s16x8 (&Acur)[8], s16x8 (&Anext)[8],
    int sidg, int didg, int& sid2, int& did2,
    const s16x8 (&bfrag)[8][4],
    const float (&b1v)[4], const float (&w2v)[4], float b2v,
    float* __restrict__ out,
    float (&lds_p)[2][2][MTILE], int pp,
    int t, int r, int c, int lg, int lr, int myrow)
{
    gatherA(hb, sidg, didg, lg, Anext);
    {
        int e = (tile + 2 * g) * MTILE + myrow;
        e = e < N_EDGES ? e : N_EDGES - 1;
        sid2 = src[e]; did2 = dst[e];
    }
    f32x4 acc[4];
    #pragma unroll
    for (int nt = 0; nt < 4; ++nt) acc[nt] = (f32x4){0.f, 0.f, 0.f, 0.f};
    #pragma unroll
    for (int kt = 0; kt < 8; ++kt)
        #pragma unroll
        for (int nt = 0; nt < 4; ++nt)
            acc[nt] = __builtin_amdgcn_mfma_f32_16x16x32_bf16(Acur[kt], bfrag[kt][nt], acc[nt], 0, 0, 0);

    float s0[4];
    #pragma unroll
    for (int rr = 0; rr < 4; ++rr) {
        float a = 0.f;
        #pragma unroll
        for (int nt = 0; nt < 4; ++nt) {
            float v = acc[nt][rr] + b1v[nt];
            v = v > 0.f ? v : 0.f;
            a += v * w2v[nt];
        }
        s0[rr] = a;
    }
    #pragma unroll
    for (int mask = 1; mask <= 8; mask <<= 1)
        #pragma unroll
        for (int rr = 0; rr < 4; ++rr)
            s0[rr] += __shfl_xor(s0[rr], mask, 64);

    if (lr == 0) {
        #pragma unroll
        for (int rr = 0; rr < 4; ++rr)
            lds_p[pp][c][r * 16 + lg * 4 + rr] = s0[rr];
    }
    asm volatile("s_waitcnt lgkmcnt(0)" ::: "memory");
    __builtin_amdgcn_s_barrier();
    asm volatile("" ::: "memory");

    if (t < MTILE) {
        int e = tile * MTILE + t;
        if (e < N_EDGES)
            out[e] = lds_p[pp][0][t] + lds_p[pp][1][t] + b2v;
    }
}

__global__ __launch_bounds__(512, 2) void mlp_edge_score_v2(
    const short* __restrict__ hb,
    const int*   __restrict__ src,
    const int*   __restrict__ dst,
    const float* __restrict__ W1,
    const float* __restrict__ b1,
    const float* __restrict__ W2,
    const float* __restrict__ b2,
    float* __restrict__ out)
{
    __shared__ float lds_p[2][2][MTILE];

    const int t  = threadIdx.x;
    const int w  = t >> 6;
    const int l  = t & 63;
    const int r  = w >> 1;
    const int c  = w & 1;
    const int lg = l >> 4;
    const int lr = l & 15;
    const int myrow = r * 16 + lr;

    s16x8 bfrag[8][4];
    #pragma unroll
    for (int kt = 0; kt < 8; ++kt)
        #pragma unroll
        for (int nt = 0; nt < 4; ++nt) {
            const int n  = c * 64 + nt * 16 + lr;
            const int kb = kt * 32 + lg * 8;
            s16x8 f;
            #pragma unroll
            for (int i = 0; i < 8; ++i) f[i] = f2bf(W1[(size_t)(kb + i) * HF + n]);
            bfrag[kt][nt] = f;
        }
    float b1v[4], w2v[4];
    #pragma unroll
    for (int nt = 0; nt < 4; ++nt) {
        const int n = c * 64 + nt * 16 + lr;
        b1v[nt] = b1[n];
        w2v[nt] = W2[n];
    }
    const float b2v = b2[0];

    const int g = gridDim.x;
    const int tile0 = blockIdx.x;

    s16x8 Aa[8], Ab[8];
    {
        int e = tile0 * MTILE + myrow;
        e = e < N_EDGES ? e : N_EDGES - 1;
        gatherA(hb, src[e], dst[e], lg, Aa);
    }
    int sidA, didA, sidB, didB;
    {
        int e = (tile0 + g) * MTILE + myrow;
        e = e < N_EDGES ? e : N_EDGES - 1;
        sidA = src[e]; didA = dst[e];
    }

    int pp = 0;
    for (int tile = tile0; tile < NTILES; tile += 2 * g) {
        step_tile_v2(tile, g, hb, src, dst, Aa, Ab, sidA, didA, sidB, didB,
                     bfrag, b1v, w2v, b2v, out, lds_p, pp, t, r, c, lg, lr, myrow);
        pp ^= 1;
        if (tile + g < NTILES) {
            step_tile_v2(tile + g, g, hb, src, dst, Ab, Aa, sidB, didB, sidA, didA,
                         bfrag, b1v, w2v, b2v, out, lds_p, pp, t, r, c, lg, lr, myrow);
            pp ^= 1;
        }
    }
}

extern "C" void kernel_launch(void* const* d_in, const int* in_sizes, int n_in,
                              void* d_out, int out_size, void* d_ws, size_t ws_size,
                              hipStream_t stream) {
    const float* h   = (const float*)d_in[0];
    const int*   src = (const int*)  d_in[1];
    const int*   dst = (const int*)  d_in[2];
    const float* W1  = (const float*)d_in[3];
    const float* b1  = (const float*)d_in[4];
    const float* W2  = (const float*)d_in[5];
    const float* b2  = (const float*)d_in[6];
    float* out = (float*)d_out;

    if (ws_size >= WS_NEED) {
        char* ws = (char*)d_ws;
        short* w1f = (short*)ws;
        short* UV  = (short*)(ws + W1F_BYTES);

        conv_w_kernel<<<16, 256, 0, stream>>>(W1, w1f);
        uv_gemm2_kernel<<<(N_NODES + 31) / 32, 512, 0, stream>>>(h, w1f, b1, UV);
        edge_combine2_kernel<<<2048, 256, 0, stream>>>(UV, src, dst, W2, b2, out);
    } else {
        short* hb = (short*)d_ws;
        const int n8 = N_NODES * HF / 8;
        conv_h_kernel<<<(n8 + 255) / 256, 256, 0, stream>>>(h, hb);
        mlp_edge_score_v2<<<256, 512, 0, stream>>>(hb, src, dst, W1, b1, W2, b2, out);
    }
}

// Round 6
// 73.143 us; speedup vs baseline: 1.4071x; 1.0126x over previous
//
#include <hip/hip_runtime.h>
#include <hip/hip_bf16.h>

#define N_NODES   50000
#define N_EDGES   625000
#define HF        128
#define MTILE     64
#define NTILES    ((N_EDGES + MTILE - 1) / MTILE)
#define HB_BYTES  ((size_t)N_NODES * HF * sizeof(short))     // v2 fallback
#define W1F_BYTES ((size_t)4096 * 16)                        // 65,536
#define UV_BYTES  ((size_t)N_NODES * 256 * sizeof(short))    // 25,600,000
#define WS_NEED   (W1F_BYTES + UV_BYTES)

typedef __attribute__((ext_vector_type(8))) short s16x8;
typedef __attribute__((ext_vector_type(4))) float f32x4;

__device__ __forceinline__ short f2bf(float x) {
    unsigned u = __builtin_bit_cast(unsigned, x);
    u += 0x7FFFu + ((u >> 16) & 1u);          // round-to-nearest-even
    return (short)(u >> 16);
}
__device__ __forceinline__ float bf2f(short s) {
    return __builtin_bit_cast(float, ((unsigned)(unsigned short)s) << 16);
}

// ---------------------------------------------------------------------------
// W -> fragment-ordered bf16. Combined B = [W1[0:128,:] | W1[128:256,:]],
// K=128, N=256 (U cols 0..127 top half of W1, V cols 128..255 bottom half).
// w1f index j = ((kt*16 + ntg)*64 + lg*16 + lr), element i:
//   k = kt*32 + lg*8 + i ; n2 = ntg*16 + lr
// ---------------------------------------------------------------------------
__global__ void conv_w_kernel(const float* __restrict__ W1, short* __restrict__ w1f) {
    int j = blockIdx.x * 256 + threadIdx.x;
    if (j < 4096) {
        const int lr  = j & 15;
        const int lg  = (j >> 4) & 3;
        const int ntg = (j >> 6) & 15;
        const int kt  = j >> 10;
        const int n2  = ntg * 16 + lr;
        const int kb  = kt * 32 + lg * 8;
        const float* wp = (n2 < 128) ? (W1 + (size_t)kb * 128 + n2)
                                     : (W1 + (size_t)(kb + 128) * 128 + (n2 - 128));
        s16x8 f;
        #pragma unroll
        for (int i = 0; i < 8; ++i) f[i] = f2bf(wp[(size_t)i * 128]);
        ((s16x8*)w1f)[j] = f;
    }
}

// ---------------------------------------------------------------------------
// UV GEMM v3: [50000 x 128] @ [128 x 256] -> UV bf16, +0.5*b1 fold.
// 256-thread block (4 waves = 4 col-quarters) owns 64 rows, looping 4
// row-sets with register-resident B fragments -> 4x VMEM amortization vs
// v2 (the ~28us was VMEM-issue-bound: 22M loads for a 3.3 GFLOP GEMM).
// Epilogue per set: LDS transpose (280-short row stride: row-groups land
// 16 banks apart, 2-way = free) -> coalesced 16B stores.
// ---------------------------------------------------------------------------
#define S_LDS 280
__global__ __launch_bounds__(256) void uv_gemm3_kernel(
    const float* __restrict__ h,
    const short* __restrict__ w1f,
    const float* __restrict__ b1,
    short* __restrict__ UV)
{
    __shared__ short ldsC[16 * S_LDS];   // 8960 B

    const int t   = threadIdx.x;
    const int chl = t >> 6;              // wave = col quarter 0..3
    const int l   = t & 63;
    const int lg  = l >> 4;
    const int lr  = l & 15;
    const int R0  = blockIdx.x * 64;

    // B fragments, loaded once per block (64 VGPR)
    s16x8 bfrag[4][4];
    #pragma unroll
    for (int kt = 0; kt < 4; ++kt)
        #pragma unroll
        for (int nt = 0; nt < 4; ++nt)
            bfrag[kt][nt] = ((const s16x8*)w1f)[(kt * 16 + chl * 4 + nt) * 64 + lg * 16 + lr];

    float b1v[4];
    #pragma unroll
    for (int nt = 0; nt < 4; ++nt)
        b1v[nt] = 0.5f * b1[(chl * 64 + nt * 16 + lr) & 127];

    #pragma unroll
    for (int rs = 0; rs < 4; ++rs) {
        // A fragments: row = R0 + rs*16 + lr, k = kt*32 + lg*8 + i
        int arow = R0 + rs * 16 + lr; if (arow > N_NODES - 1) arow = N_NODES - 1;
        const float* hp = h + (size_t)arow * HF + lg * 8;
        s16x8 afr[4];
        #pragma unroll
        for (int kt = 0; kt < 4; ++kt) {
            f32x4 a = *reinterpret_cast<const f32x4*>(hp + kt * 32);
            f32x4 b = *reinterpret_cast<const f32x4*>(hp + kt * 32 + 4);
            s16x8 p;
            p[0]=f2bf(a[0]); p[1]=f2bf(a[1]); p[2]=f2bf(a[2]); p[3]=f2bf(a[3]);
            p[4]=f2bf(b[0]); p[5]=f2bf(b[1]); p[6]=f2bf(b[2]); p[7]=f2bf(b[3]);
            afr[kt] = p;
        }

        f32x4 acc[4];
        #pragma unroll
        for (int nt = 0; nt < 4; ++nt) acc[nt] = (f32x4){0.f, 0.f, 0.f, 0.f};
        #pragma unroll
        for (int kt = 0; kt < 4; ++kt)
            #pragma unroll
            for (int nt = 0; nt < 4; ++nt)
                acc[nt] = __builtin_amdgcn_mfma_f32_16x16x32_bf16(afr[kt], bfrag[kt][nt], acc[nt], 0, 0, 0);

        // epilogue: acc -> LDS (bf16, +bias). C/D: col = lr, row = lg*4 + rr.
        #pragma unroll
        for (int nt = 0; nt < 4; ++nt) {
            const int col = chl * 64 + nt * 16 + lr;
            #pragma unroll
            for (int rr = 0; rr < 4; ++rr)
                ldsC[(lg * 4 + rr) * S_LDS + col] = f2bf(acc[nt][rr] + b1v[nt]);
        }
        __syncthreads();

        // coalesced store: 16 rows x 32 chunks x 16B = 512 chunks, 2/thread
        #pragma unroll
        for (int i = 0; i < 2; ++i) {
            const int idx = t + i * 256;
            const int r2 = idx >> 5, ch = idx & 31;
            const int grow = R0 + rs * 16 + r2;
            if (grow < N_NODES) {
                s16x8 vv = *reinterpret_cast<const s16x8*>(&ldsC[r2 * S_LDS + ch * 8]);
                *reinterpret_cast<s16x8*>(&UV[(size_t)grow * 256 + ch * 8]) = vv;
            }
        }
        __syncthreads();
    }
}

// ---------------------------------------------------------------------------
// Edge combine (unchanged from round 5, stable 42us): out[e] =
// sum_d relu(U[src][d] + V[dst][d]) * W2[d] + b2.
// 8 lanes/edge x 16 dims/lane; 32 edges per wave-iter; ids deduped via one
// coalesced load + shfl broadcast; next-iter ids prefetched under compute.
// ---------------------------------------------------------------------------
__device__ __forceinline__ float dotrelu8(s16x8 u, s16x8 v, const float* w2v, int off) {
    float a = 0.f;
    #pragma unroll
    for (int j = 0; j < 8; ++j) {
        float s = bf2f(u[j]) + bf2f(v[j]);
        s = s > 0.f ? s : 0.f;
        a += s * w2v[off + j];
    }
    return a;
}

__global__ __launch_bounds__(256) void edge_combine2_kernel(
    const short* __restrict__ UV,
    const int*   __restrict__ src,
    const int*   __restrict__ dst,
    const float* __restrict__ W2,
    const float* __restrict__ b2,
    float* __restrict__ out)
{
    const int t  = threadIdx.x;
    const int w  = t >> 6;
    const int l  = t & 63;
    const int eg = l >> 3;         // edge-in-sub-batch 0..7
    const int dg = l & 7;          // dim group 0..7
    const int dl = dg * 16;        // dim base

    float w2v[16];
    #pragma unroll
    for (int j = 0; j < 16; ++j) w2v[j] = W2[dl + j];
    const float b2v = b2[0];

    const int gw = blockIdx.x * 4 + w;
    const int stride = gridDim.x * 4 * 32;

    int base = gw * 32;
    int jj0 = base + (l & 31); if (jj0 > N_EDGES - 1) jj0 = N_EDGES - 1;
    int ids = (l < 32) ? src[jj0] : dst[jj0];

    for (; base < N_EDGES; base += stride) {
        int s[4], d[4];
        #pragma unroll
        for (int k = 0; k < 4; ++k) {
            s[k] = __shfl(ids, k * 8 + eg, 64);
            d[k] = __shfl(ids, 32 + k * 8 + eg, 64);
        }

        // issue all 16 gathers before any consume (16 x 16B in flight)
        s16x8 u0[4], u1[4], v0[4], v1[4];
        #pragma unroll
        for (int k = 0; k < 4; ++k) {
            const s16x8* up = (const s16x8*)(UV + (size_t)s[k] * 256 + dl);
            const s16x8* vp = (const s16x8*)(UV + (size_t)d[k] * 256 + 128 + dl);
            u0[k] = up[0]; u1[k] = up[1];
            v0[k] = vp[0]; v1[k] = vp[1];
        }

        // prefetch next iteration's ids under the gather latency
        const int nb = base + stride;
        if (nb < N_EDGES) {
            int j2 = nb + (l & 31); if (j2 > N_EDGES - 1) j2 = N_EDGES - 1;
            ids = (l < 32) ? src[j2] : dst[j2];
        }

        float a[4];
        #pragma unroll
        for (int k = 0; k < 4; ++k)
            a[k] = dotrelu8(u0[k], v0[k], w2v, 0) + dotrelu8(u1[k], v1[k], w2v, 8);

        #pragma unroll
        for (int m = 1; m <= 4; m <<= 1)
            #pragma unroll
            for (int k = 0; k < 4; ++k)
                a[k] += __shfl_xor(a[k], m, 64);

        if (dg == 0) {
            #pragma unroll
            for (int k = 0; k < 4; ++k) {
                const int ei = base + k * 8 + eg;
                if (ei < N_EDGES) __builtin_nontemporal_store(a[k] + b2v, &out[ei]);
            }
        }
    }
}

// ---------------------------------------------------------------------------
// v2 fallback (only if ws too small): bf16 h + direct-gather MFMA
// ---------------------------------------------------------------------------
__global__ void conv_h_kernel(const float* __restrict__ h, short* __restrict__ hb) {
    int i = blockIdx.x * blockDim.x + threadIdx.x;
    const int n8 = N_NODES * HF / 8;
    if (i < n8) {
        f32x4 a = ((const f32x4*)h)[i * 2];
        f32x4 b = ((const f32x4*)h)[i * 2 + 1];
        s16x8 p;
        p[0]=f2bf(a[0]); p[1]=f2bf(a[1]); p[2]=f2bf(a[2]); p[3]=f2bf(a[3]);
        p[4]=f2bf(b[0]); p[5]=f2bf(b[1]); p[6]=f2bf(b[2]); p[7]=f2bf(b[3]);
        ((s16x8*)hb)[i] = p;
    }
}

__device__ __forceinline__ void gatherA(const short* __restrict__ hb,
                                        int sid, int did, int lg, s16x8 (&A)[8]) {
    const s16x8* bs = (const s16x8*)(hb + (size_t)sid * HF);
    const s16x8* bd = (const s16x8*)(hb + (size_t)did * HF);
    A[0] = bs[lg];      A[1] = bs[4 + lg];  A[2] = bs[8 + lg];  A[3] = bs[12 + lg];
    A[4] = bd[lg];      A[5] = bd[4 + lg];  A[6] = bd[8 + lg];  A[7] = bd[12 + lg];
}

__device__ __forceinline__ void step_tile_v2(
    int tile, int g,
    const short* __restrict__ hb,
    const int* __restrict__ src, const int* __restrict__ dst,
    s16x8 (&Acur)[8], s16x8 (&Anext)[8],
    int sidg, int didg, int& sid2, int& did2,
    const s16x8 (&bfrag)[8][4],
    const float (&b1v)[4], const float (&w2v)[4], float b2v,
    float* __restrict__ out,
    float (&lds_p)[2][2][MTILE], int pp,
    int t, int r, int c, int lg, int lr, int myrow)
{
    gatherA(hb, sidg, didg, lg, Anext);
    {
        int e = (tile + 2 * g) * MTILE + myrow;
        e = e < N_EDGES ? e : N_EDGES - 1;
        sid2 = src[e]; did2 = dst[e];
    }
    f32x4 acc[4];
    #pragma unroll
    for (int nt = 0; nt < 4; ++nt) acc[nt] = (f32x4){0.f, 0.f, 0.f, 0.f};
    #pragma unroll
    for (int kt = 0; kt < 8; ++kt)
        #pragma unroll
        for (int nt = 0; nt < 4; ++nt)
            acc[nt] = __builtin_amdgcn_mfma_f32_16x16x32_bf16(Acur[kt], bfrag[kt][nt], acc[nt], 0, 0, 0);

    float s0[4];
    #pragma unroll
    for (int rr = 0; rr < 4; ++rr) {
        float a = 0.f;
        #pragma unroll
        for (int nt = 0; nt < 4; ++nt) {
            float v = acc[nt][rr] + b1v[nt];
            v = v > 0.f ? v : 0.f;
            a += v * w2v[nt];
        }
        s0[rr] = a;
    }
    #pragma unroll
    for (int mask = 1; mask <= 8; mask <<= 1)
        #pragma unroll
        for (int rr = 0; rr < 4; ++rr)
            s0[rr] += __shfl_xor(s0[rr], mask, 64);

    if (lr == 0) {
        #pragma unroll
        for (int rr = 0; rr < 4; ++rr)
            lds_p[pp][c][r * 16 + lg * 4 + rr] = s0[rr];
    }
    asm volatile("s_waitcnt lgkmcnt(0)" ::: "memory");
    __builtin_amdgcn_s_barrier();
    asm volatile("" ::: "memory");

    if (t < MTILE) {
        int e = tile * MTILE + t;
        if (e < N_EDGES)
            out[e] = lds_p[pp][0][t] + lds_p[pp][1][t] + b2v;
    }
}

__global__ __launch_bounds__(512, 2) void mlp_edge_score_v2(
    const short* __restrict__ hb,
    const int*   __restrict__ src,
    const int*   __restrict__ dst,
    const float* __restrict__ W1,
    const float* __restrict__ b1,
    const float* __restrict__ W2,
    const float* __restrict__ b2,
    float* __restrict__ out)
{
    __shared__ float lds_p[2][2][MTILE];

    const int t  = threadIdx.x;
    const int w  = t >> 6;
    const int l  = t & 63;
    const int r  = w >> 1;
    const int c  = w & 1;
    const int lg = l >> 4;
    const int lr = l & 15;
    const int myrow = r * 16 + lr;

    s16x8 bfrag[8][4];
    #pragma unroll
    for (int kt = 0; kt < 8; ++kt)
        #pragma unroll
        for (int nt = 0; nt < 4; ++nt) {
            const int n  = c * 64 + nt * 16 + lr;
            const int kb = kt * 32 + lg * 8;
            s16x8 f;
            #pragma unroll
            for (int i = 0; i < 8; ++i) f[i] = f2bf(W1[(size_t)(kb + i) * HF + n]);
            bfrag[kt][nt] = f;
        }
    float b1v[4], w2v[4];
    #pragma unroll
    for (int nt = 0; nt < 4; ++nt) {
        const int n = c * 64 + nt * 16 + lr;
        b1v[nt] = b1[n];
        w2v[nt] = W2[n];
    }
    const float b2v = b2[0];

    const int g = gridDim.x;
    const int tile0 = blockIdx.x;

    s16x8 Aa[8], Ab[8];
    {
        int e = tile0 * MTILE + myrow;
        e = e < N_EDGES ? e : N_EDGES - 1;
        gatherA(hb, src[e], dst[e], lg, Aa);
    }
    int sidA, didA, sidB, didB;
    {
        int e = (tile0 + g) * MTILE + myrow;
        e = e < N_EDGES ? e : N_EDGES - 1;
        sidA = src[e]; didA = dst[e];
    }

    int pp = 0;
    for (int tile = tile0; tile < NTILES; tile += 2 * g) {
        step_tile_v2(tile, g, hb, src, dst, Aa, Ab, sidA, didA, sidB, didB,
                     bfrag, b1v, w2v, b2v, out, lds_p, pp, t, r, c, lg, lr, myrow);
        pp ^= 1;
        if (tile + g < NTILES) {
            step_tile_v2(tile + g, g, hb, src, dst, Ab, Aa, sidB, didB, sidA, didA,
                         bfrag, b1v, w2v, b2v, out, lds_p, pp, t, r, c, lg, lr, myrow);
            pp ^= 1;
        }
    }
}

extern "C" void kernel_launch(void* const* d_in, const int* in_sizes, int n_in,
                              void* d_out, int out_size, void* d_ws, size_t ws_size,
                              hipStream_t stream) {
    const float* h   = (const float*)d_in[0];
    const int*   src = (const int*)  d_in[1];
    const int*   dst = (const int*)  d_in[2];
    const float* W1  = (const float*)d_in[3];
    const float* b1  = (const float*)d_in[4];
    const float* W2  = (const float*)d_in[5];
    const float* b2  = (const float*)d_in[6];
    float* out = (float*)d_out;

    if (ws_size >= WS_NEED) {
        char* ws = (char*)d_ws;
        short* w1f = (short*)ws;
        short* UV  = (short*)(ws + W1F_BYTES);

        conv_w_kernel<<<16, 256, 0, stream>>>(W1, w1f);
        uv_gemm3_kernel<<<(N_NODES + 63) / 64, 256, 0, stream>>>(h, w1f, b1, UV);
        edge_combine2_kernel<<<2048, 256, 0, stream>>>(UV, src, dst, W2, b2, out);
    } else {
        short* hb = (short*)d_ws;
        const int n8 = N_NODES * HF / 8;
        conv_h_kernel<<<(n8 + 255) / 256, 256, 0, stream>>>(h, hb);
        mlp_edge_score_v2<<<256, 512, 0, stream>>>(hb, src, dst, W1, b1, W2, b2, out);
    }
}

// Round 7
// 68.660 us; speedup vs baseline: 1.4990x; 1.0653x over previous
//
#include <hip/hip_runtime.h>
#include <hip/hip_bf16.h>

#define N_NODES   50000
#define N_EDGES   625000
#define HF        128
#define MTILE     64
#define NTILES    ((N_EDGES + MTILE - 1) / MTILE)
#define HB_BYTES  ((size_t)N_NODES * HF * sizeof(short))     // v2 fallback
#define W1F_BYTES ((size_t)4096 * 16)                        // 65,536
#define UV_BYTES  ((size_t)N_NODES * 256 * sizeof(short))    // 25,600,000
#define WS_NEED   (W1F_BYTES + UV_BYTES)
#define E_SPLIT   312512                                     // 32-aligned half

typedef __attribute__((ext_vector_type(8))) short s16x8;
typedef __attribute__((ext_vector_type(4))) float f32x4;

__device__ __forceinline__ short f2bf(float x) {
    unsigned u = __builtin_bit_cast(unsigned, x);
    u += 0x7FFFu + ((u >> 16) & 1u);          // round-to-nearest-even
    return (short)(u >> 16);
}
__device__ __forceinline__ float bf2f(short s) {
    return __builtin_bit_cast(float, ((unsigned)(unsigned short)s) << 16);
}

// ---------------------------------------------------------------------------
// W -> fragment-ordered bf16. Combined B = [W1[0:128,:] | W1[128:256,:]],
// K=128, N=256 (U cols 0..127 top half of W1, V cols 128..255 bottom half).
// w1f index j = ((kt*16 + ntg)*64 + lg*16 + lr), element i:
//   k = kt*32 + lg*8 + i ; n2 = ntg*16 + lr
// ---------------------------------------------------------------------------
__global__ void conv_w_kernel(const float* __restrict__ W1, short* __restrict__ w1f) {
    int j = blockIdx.x * 256 + threadIdx.x;
    if (j < 4096) {
        const int lr  = j & 15;
        const int lg  = (j >> 4) & 3;
        const int ntg = (j >> 6) & 15;
        const int kt  = j >> 10;
        const int n2  = ntg * 16 + lr;
        const int kb  = kt * 32 + lg * 8;
        const float* wp = (n2 < 128) ? (W1 + (size_t)kb * 128 + n2)
                                     : (W1 + (size_t)(kb + 128) * 128 + (n2 - 128));
        s16x8 f;
        #pragma unroll
        for (int i = 0; i < 8; ++i) f[i] = f2bf(wp[(size_t)i * 128]);
        ((s16x8*)w1f)[j] = f;
    }
}

// ---------------------------------------------------------------------------
// UV GEMM v4: barrier-free, wave-independent. Wave = 16 rows x 128 cols.
// - A staged via fully-coalesced 1KB loads into a private XOR-swizzled LDS
//   slice (fixes the strided 32-line row-gather TA cost of v1-v3).
// - Two nt-half passes keep VGPR ~160 (bfrag 64 + acc 16 live at a time).
// - Epilogue through swizzled bf16 LDS slice -> coalesced 16B stores.
// No __syncthreads anywhere; per-wave LDS slices are disjoint.
// ---------------------------------------------------------------------------
__global__ __launch_bounds__(256) void uv_gemm4_kernel(
    const float* __restrict__ h,
    const short* __restrict__ w1f,
    const float* __restrict__ b1,
    short* __restrict__ UV)
{
    // per-wave: A f32 tile 16x512B (swizzled) + C bf16 tile 16x256B (swizzled)
    __shared__ char lds[4 * (8192 + 4096)];   // 48 KiB

    const int t  = threadIdx.x;
    const int w  = t >> 6;
    const int l  = t & 63;
    const int lg = l >> 4;
    const int lr = l & 15;
    const int rgrp  = w >> 1;       // 0/1: row sub-tile
    const int chalf = w & 1;        // 0/1: col half (128 cols)
    const int R0 = blockIdx.x * 32 + rgrp * 16;

    char* Abase = lds + w * 12288;
    char* Cbase = Abase + 8192;

    // ---- stage A: 16 rows x 512 B contiguous, perfectly coalesced ----
    #pragma unroll
    for (int i = 0; i < 8; ++i) {
        int r = R0 + i * 2 + (l >> 5);
        if (r > N_NODES - 1) r = N_NODES - 1;
        f32x4 v = *reinterpret_cast<const f32x4*>(h + (size_t)r * HF + (l & 31) * 4);
        const int lrow  = i * 2 + (l >> 5);
        const int col16 = (l & 31) * 16;
        *reinterpret_cast<f32x4*>(Abase + lrow * 512 + (col16 ^ ((lrow & 7) << 4))) = v;
    }

    // ---- A fragments from LDS (swizzled reads, conflict-free) ----
    // afr[kt] elem i = A[row lr][k = kt*32 + lg*8 + i]
    s16x8 afr[4];
    {
        const int sw = (lr & 7) << 4;
        #pragma unroll
        for (int kt = 0; kt < 4; ++kt) {
            f32x4 a = *reinterpret_cast<const f32x4*>(Abase + lr * 512 + ((kt * 128 + lg * 32) ^ sw));
            f32x4 b = *reinterpret_cast<const f32x4*>(Abase + lr * 512 + ((kt * 128 + lg * 32 + 16) ^ sw));
            s16x8 p;
            p[0]=f2bf(a[0]); p[1]=f2bf(a[1]); p[2]=f2bf(a[2]); p[3]=f2bf(a[3]);
            p[4]=f2bf(b[0]); p[5]=f2bf(b[1]); p[6]=f2bf(b[2]); p[7]=f2bf(b[3]);
            afr[kt] = p;
        }
    }

    // ---- two nt-half passes: 4 nt each (64 cols), bfrag 16 frags live ----
    #pragma unroll
    for (int nh = 0; nh < 2; ++nh) {
        s16x8 bfrag[4][4];
        #pragma unroll
        for (int kt = 0; kt < 4; ++kt)
            #pragma unroll
            for (int nt = 0; nt < 4; ++nt)
                bfrag[kt][nt] = ((const s16x8*)w1f)[(kt * 16 + chalf * 8 + nh * 4 + nt) * 64 + l];

        f32x4 acc[4];
        #pragma unroll
        for (int nt = 0; nt < 4; ++nt) acc[nt] = (f32x4){0.f, 0.f, 0.f, 0.f};
        #pragma unroll
        for (int kt = 0; kt < 4; ++kt)
            #pragma unroll
            for (int nt = 0; nt < 4; ++nt)
                acc[nt] = __builtin_amdgcn_mfma_f32_16x16x32_bf16(afr[kt], bfrag[kt][nt], acc[nt], 0, 0, 0);

        // C -> LDS bf16 (+0.5*b1). C/D: col = lr, row = lg*4 + rr.
        #pragma unroll
        for (int nt = 0; nt < 4; ++nt) {
            const float bh = 0.5f * b1[(chalf * 128 + (nh * 4 + nt) * 16 + lr) & 127];
            const int colb = (nh * 4 + nt) * 32 + lr * 2;   // byte col within 256
            #pragma unroll
            for (int rr = 0; rr < 4; ++rr) {
                const int row = lg * 4 + rr;
                *(short*)(Cbase + row * 256 + (colb ^ ((row & 7) << 4))) = f2bf(acc[nt][rr] + bh);
            }
        }
    }

    // ---- C read (swizzled) -> coalesced 16B UV stores ----
    #pragma unroll
    for (int i = 0; i < 4; ++i) {
        const int r2  = i * 4 + (l >> 4);
        const int c16 = (l & 15) * 16;
        s16x8 vv = *reinterpret_cast<const s16x8*>(Cbase + r2 * 256 + (c16 ^ ((r2 & 7) << 4)));
        const int grow = R0 + r2;
        if (grow < N_NODES)
            *reinterpret_cast<s16x8*>(&UV[(size_t)grow * 256 + chalf * 128 + (l & 15) * 8]) = vv;
    }
}

// ---------------------------------------------------------------------------
// Edge combine (structure unchanged; runtime count so it can run as two
// half-range dispatches): out[e] = sum_d relu(U[src][d]+V[dst][d])*W2[d]+b2
// ---------------------------------------------------------------------------
__device__ __forceinline__ float dotrelu8(s16x8 u, s16x8 v, const float* w2v, int off) {
    float a = 0.f;
    #pragma unroll
    for (int j = 0; j < 8; ++j) {
        float s = bf2f(u[j]) + bf2f(v[j]);
        s = s > 0.f ? s : 0.f;
        a += s * w2v[off + j];
    }
    return a;
}

__global__ __launch_bounds__(256) void edge_combine2_kernel(
    const short* __restrict__ UV,
    const int*   __restrict__ src,
    const int*   __restrict__ dst,
    const float* __restrict__ W2,
    const float* __restrict__ b2,
    float* __restrict__ out,
    int nE)
{
    const int t  = threadIdx.x;
    const int w  = t >> 6;
    const int l  = t & 63;
    const int eg = l >> 3;         // edge-in-sub-batch 0..7
    const int dg = l & 7;          // dim group 0..7
    const int dl = dg * 16;        // dim base

    float w2v[16];
    #pragma unroll
    for (int j = 0; j < 16; ++j) w2v[j] = W2[dl + j];
    const float b2v = b2[0];

    const int gw = blockIdx.x * 4 + w;
    const int stride = gridDim.x * 4 * 32;

    int base = gw * 32;
    int jj0 = base + (l & 31); if (jj0 > nE - 1) jj0 = nE - 1;
    int ids = (l < 32) ? src[jj0] : dst[jj0];

    for (; base < nE; base += stride) {
        int s[4], d[4];
        #pragma unroll
        for (int k = 0; k < 4; ++k) {
            s[k] = __shfl(ids, k * 8 + eg, 64);
            d[k] = __shfl(ids, 32 + k * 8 + eg, 64);
        }

        // issue all 16 gathers before any consume (16 x 16B in flight)
        s16x8 u0[4], u1[4], v0[4], v1[4];
        #pragma unroll
        for (int k = 0; k < 4; ++k) {
            const s16x8* up = (const s16x8*)(UV + (size_t)s[k] * 256 + dl);
            const s16x8* vp = (const s16x8*)(UV + (size_t)d[k] * 256 + 128 + dl);
            u0[k] = up[0]; u1[k] = up[1];
            v0[k] = vp[0]; v1[k] = vp[1];
        }

        // prefetch next iteration's ids under the gather latency
        const int nb = base + stride;
        if (nb < nE) {
            int j2 = nb + (l & 31); if (j2 > nE - 1) j2 = nE - 1;
            ids = (l < 32) ? src[j2] : dst[j2];
        }

        float a[4];
        #pragma unroll
        for (int k = 0; k < 4; ++k)
            a[k] = dotrelu8(u0[k], v0[k], w2v, 0) + dotrelu8(u1[k], v1[k], w2v, 8);

        #pragma unroll
        for (int m = 1; m <= 4; m <<= 1)
            #pragma unroll
            for (int k = 0; k < 4; ++k)
                a[k] += __shfl_xor(a[k], m, 64);

        if (dg == 0) {
            #pragma unroll
            for (int k = 0; k < 4; ++k) {
                const int ei = base + k * 8 + eg;
                if (ei < nE) __builtin_nontemporal_store(a[k] + b2v, &out[ei]);
            }
        }
    }
}

// ---------------------------------------------------------------------------
// v2 fallback (only if ws too small): bf16 h + direct-gather MFMA
// ---------------------------------------------------------------------------
__global__ void conv_h_kernel(const float* __restrict__ h, short* __restrict__ hb) {
    int i = blockIdx.x * blockDim.x + threadIdx.x;
    const int n8 = N_NODES * HF / 8;
    if (i < n8) {
        f32x4 a = ((const f32x4*)h)[i * 2];
        f32x4 b = ((const f32x4*)h)[i * 2 + 1];
        s16x8 p;
        p[0]=f2bf(a[0]); p[1]=f2bf(a[1]); p[2]=f2bf(a[2]); p[3]=f2bf(a[3]);
        p[4]=f2bf(b[0]); p[5]=f2bf(b[1]); p[6]=f2bf(b[2]); p[7]=f2bf(b[3]);
        ((s16x8*)hb)[i] = p;
    }
}

__device__ __forceinline__ void gatherA(const short* __restrict__ hb,
                                        int sid, int did, int lg, s16x8 (&A)[8]) {
    const s16x8* bs = (const s16x8*)(hb + (size_t)sid * HF);
    const s16x8* bd = (const s16x8*)(hb + (size_t)did * HF);
    A[0] = bs[lg];      A[1] = bs[4 + lg];  A[2] = bs[8 + lg];  A[3] = bs[12 + lg];
    A[4] = bd[lg];      A[5] = bd[4 + lg];  A[6] = bd[8 + lg];  A[7] = bd[12 + lg];
}

__device__ __forceinline__ void step_tile_v2(
    int tile, int g,
    const short* __restrict__ hb,
    const int* __restrict__ src, const int* __restrict__ dst,
    s16x8 (&Acur)[8], s16x8 (&Anext)[8],
    int sidg, int didg, int& sid2, int& did2,
    const s16x8 (&bfrag)[8][4],
    const float (&b1v)[4], const float (&w2v)[4], float b2v,
    float* __restrict__ out,
    float (&lds_p)[2][2][MTILE], int pp,
    int t, int r, int c, int lg, int lr, int myrow)
{
    gatherA(hb, sidg, didg, lg, Anext);
    {
        int e = (tile + 2 * g) * MTILE + myrow;
        e = e < N_EDGES ? e : N_EDGES - 1;
        sid2 = src[e]; did2 = dst[e];
    }
    f32x4 acc[4];
    #pragma unroll
    for (int nt = 0; nt < 4; ++nt) acc[nt] = (f32x4){0.f, 0.f, 0.f, 0.f};
    #pragma unroll
    for (int kt = 0; kt < 8; ++kt)
        #pragma unroll
        for (int nt = 0; nt < 4; ++nt)
            acc[nt] = __builtin_amdgcn_mfma_f32_16x16x32_bf16(Acur[kt], bfrag[kt][nt], acc[nt], 0, 0, 0);

    float s0[4];
    #pragma unroll
    for (int rr = 0; rr < 4; ++rr) {
        float a = 0.f;
        #pragma unroll
        for (int nt = 0; nt < 4; ++nt) {
            float v = acc[nt][rr] + b1v[nt];
            v = v > 0.f ? v : 0.f;
            a += v * w2v[nt];
        }
        s0[rr] = a;
    }
    #pragma unroll
    for (int mask = 1; mask <= 8; mask <<= 1)
        #pragma unroll
        for (int rr = 0; rr < 4; ++rr)
            s0[rr] += __shfl_xor(s0[rr], mask, 64);

    if (lr == 0) {
        #pragma unroll
        for (int rr = 0; rr < 4; ++rr)
            lds_p[pp][c][r * 16 + lg * 4 + rr] = s0[rr];
    }
    asm volatile("s_waitcnt lgkmcnt(0)" ::: "memory");
    __builtin_amdgcn_s_barrier();
    asm volatile("" ::: "memory");

    if (t < MTILE) {
        int e = tile * MTILE + t;
        if (e < N_EDGES)
            out[e] = lds_p[pp][0][t] + lds_p[pp][1][t] + b2v;
    }
}

__global__ __launch_bounds__(512, 2) void mlp_edge_score_v2(
    const short* __restrict__ hb,
    const int*   __restrict__ src,
    const int*   __restrict__ dst,
    const float* __restrict__ W1,
    const float* __restrict__ b1,
    const float* __restrict__ W2,
    const float* __restrict__ b2,
    float* __restrict__ out)
{
    __shared__ float lds_p[2][2][MTILE];

    const int t  = threadIdx.x;
    const int w  = t >> 6;
    const int l  = t & 63;
    const int r  = w >> 1;
    const int c  = w & 1;
    const int lg = l >> 4;
    const int lr = l & 15;
    const int myrow = r * 16 + lr;

    s16x8 bfrag[8][4];
    #pragma unroll
    for (int kt = 0; kt < 8; ++kt)
        #pragma unroll
        for (int nt = 0; nt < 4; ++nt) {
            const int n  = c * 64 + nt * 16 + lr;
            const int kb = kt * 32 + lg * 8;
            s16x8 f;
            #pragma unroll
            for (int i = 0; i < 8; ++i) f[i] = f2bf(W1[(size_t)(kb + i) * HF + n]);
            bfrag[kt][nt] = f;
        }
    float b1v[4], w2v[4];
    #pragma unroll
    for (int nt = 0; nt < 4; ++nt) {
        const int n = c * 64 + nt * 16 + lr;
        b1v[nt] = b1[n];
        w2v[nt] = W2[n];
    }
    const float b2v = b2[0];

    const int g = gridDim.x;
    const int tile0 = blockIdx.x;

    s16x8 Aa[8], Ab[8];
    {
        int e = tile0 * MTILE + myrow;
        e = e < N_EDGES ? e : N_EDGES - 1;
        gatherA(hb, src[e], dst[e], lg, Aa);
    }
    int sidA, didA, sidB, didB;
    {
        int e = (tile0 + g) * MTILE + myrow;
        e = e < N_EDGES ? e : N_EDGES - 1;
        sidA = src[e]; didA = dst[e];
    }

    int pp = 0;
    for (int tile = tile0; tile < NTILES; tile += 2 * g) {
        step_tile_v2(tile, g, hb, src, dst, Aa, Ab, sidA, didA, sidB, didB,
                     bfrag, b1v, w2v, b2v, out, lds_p, pp, t, r, c, lg, lr, myrow);
        pp ^= 1;
        if (tile + g < NTILES) {
            step_tile_v2(tile + g, g, hb, src, dst, Ab, Aa, sidB, didB, sidA, didA,
                         bfrag, b1v, w2v, b2v, out, lds_p, pp, t, r, c, lg, lr, myrow);
            pp ^= 1;
        }
    }
}

extern "C" void kernel_launch(void* const* d_in, const int* in_sizes, int n_in,
                              void* d_out, int out_size, void* d_ws, size_t ws_size,
                              hipStream_t stream) {
    const float* h   = (const float*)d_in[0];
    const int*   src = (const int*)  d_in[1];
    const int*   dst = (const int*)  d_in[2];
    const float* W1  = (const float*)d_in[3];
    const float* b1  = (const float*)d_in[4];
    const float* W2  = (const float*)d_in[5];
    const float* b2  = (const float*)d_in[6];
    float* out = (float*)d_out;

    if (ws_size >= WS_NEED) {
        char* ws = (char*)d_ws;
        short* w1f = (short*)ws;
        short* UV  = (short*)(ws + W1F_BYTES);

        conv_w_kernel<<<16, 256, 0, stream>>>(W1, w1f);
        uv_gemm4_kernel<<<(N_NODES + 31) / 32, 256, 0, stream>>>(h, w1f, b1, UV);
        edge_combine2_kernel<<<1024, 256, 0, stream>>>(UV, src, dst, W2, b2, out, E_SPLIT);
        edge_combine2_kernel<<<1024, 256, 0, stream>>>(UV, src + E_SPLIT, dst + E_SPLIT,
                                                       W2, b2, out + E_SPLIT, N_EDGES - E_SPLIT);
    } else {
        short* hb = (short*)d_ws;
        const int n8 = N_NODES * HF / 8;
        conv_h_kernel<<<(n8 + 255) / 256, 256, 0, stream>>>(h, hb);
        mlp_edge_score_v2<<<256, 512, 0, stream>>>(hb, src, dst, W1, b1, W2, b2, out);
    }
}

// Round 8
// 62.112 us; speedup vs baseline: 1.6570x; 1.1054x over previous
//
#include <hip/hip_runtime.h>
#include <hip/hip_bf16.h>

#define N_NODES   50000
#define N_EDGES   625000
#define HF        128
#define MTILE     64
#define NTILES    ((N_EDGES + MTILE - 1) / MTILE)
#define HB_BYTES  ((size_t)N_NODES * HF * sizeof(short))     // v2 fallback
#define W1F_BYTES ((size_t)4096 * 16)                        // 65,536
#define UV_BYTES  ((size_t)N_NODES * 256 * sizeof(short))    // 25,600,000
#define WS_NEED   (W1F_BYTES + UV_BYTES)
#define NROWTILES ((N_NODES + 15) / 16)                      // 3125

typedef __attribute__((ext_vector_type(8))) short s16x8;
typedef __attribute__((ext_vector_type(4))) float f32x4;

__device__ __forceinline__ short f2bf(float x) {
    unsigned u = __builtin_bit_cast(unsigned, x);
    u += 0x7FFFu + ((u >> 16) & 1u);          // round-to-nearest-even
    return (short)(u >> 16);
}
__device__ __forceinline__ float bf2f(short s) {
    return __builtin_bit_cast(float, ((unsigned)(unsigned short)s) << 16);
}

// ---------------------------------------------------------------------------
// W -> fragment-ordered bf16. Combined B = [W1[0:128,:] | W1[128:256,:]],
// K=128, N=256 (U cols 0..127 top half of W1, V cols 128..255 bottom half).
// w1f index j = ((kt*16 + ntg)*64 + lg*16 + lr), element i:
//   k = kt*32 + lg*8 + i ; n2 = ntg*16 + lr
// ---------------------------------------------------------------------------
__global__ void conv_w_kernel(const float* __restrict__ W1, short* __restrict__ w1f) {
    int j = blockIdx.x * 256 + threadIdx.x;
    if (j < 4096) {
        const int lr  = j & 15;
        const int lg  = (j >> 4) & 3;
        const int ntg = (j >> 6) & 15;
        const int kt  = j >> 10;
        const int n2  = ntg * 16 + lr;
        const int kb  = kt * 32 + lg * 8;
        const float* wp = (n2 < 128) ? (W1 + (size_t)kb * 128 + n2)
                                     : (W1 + (size_t)(kb + 128) * 128 + (n2 - 128));
        s16x8 f;
        #pragma unroll
        for (int i = 0; i < 8; ++i) f[i] = f2bf(wp[(size_t)i * 128]);
        ((s16x8*)w1f)[j] = f;
    }
}

// ---------------------------------------------------------------------------
// UV GEMM v5: weights-stationary persistent. 4 waves = 4 col-quarters;
// bfrag loaded ONCE per wave (cuts w1f traffic 6x). Loop over 16-row tiles:
//   stage A once per block as bf16 into 4KB swizzled LDS (f2bf at stage
//   time; fragment read = one ds_read_b128, bank-optimal), 16 MFMA,
//   epilogue via per-wave swizzled LDS slice -> coalesced 16B UV stores.
// ---------------------------------------------------------------------------
__global__ __launch_bounds__(256, 4) void uv_gemm5_kernel(
    const float* __restrict__ h,
    const short* __restrict__ w1f,
    const float* __restrict__ b1,
    short* __restrict__ UV)
{
    __shared__ short ldsA[16 * 128];     // 4 KB bf16 A tile (swizzled)
    __shared__ char  ldsC[4][2048];      // per-wave C slices 16 x 128B (swizzled)

    const int t  = threadIdx.x;
    const int w  = t >> 6;               // wave = col quarter 0..3
    const int l  = t & 63;
    const int lg = l >> 4;
    const int lr = l & 15;

    // resident B fragments for this wave's 64 cols (64 VGPR), loaded once
    s16x8 bfrag[4][4];
    #pragma unroll
    for (int kt = 0; kt < 4; ++kt)
        #pragma unroll
        for (int nt = 0; nt < 4; ++nt)
            bfrag[kt][nt] = ((const s16x8*)w1f)[(kt * 16 + w * 4 + nt) * 64 + l];

    float b1v[4];
    #pragma unroll
    for (int nt = 0; nt < 4; ++nt)
        b1v[nt] = 0.5f * b1[(w * 64 + nt * 16 + lr) & 127];

    // stage-thread mapping: row = t>>4 (0..15), 16B-bf16 chunk = t&15 (0..15)
    const int srow = t >> 4;
    const int sch  = t & 15;

    for (int tile = blockIdx.x; tile < NROWTILES; tile += gridDim.x) {
        const int R0 = tile * 16;

        // ---- stage A: 16 rows x 256B bf16, one chunk per thread ----
        {
            int gr = R0 + srow; if (gr > N_NODES - 1) gr = N_NODES - 1;
            const float* hp = h + (size_t)gr * HF + sch * 8;
            f32x4 a = *reinterpret_cast<const f32x4*>(hp);
            f32x4 b = *reinterpret_cast<const f32x4*>(hp + 4);
            s16x8 p;
            p[0]=f2bf(a[0]); p[1]=f2bf(a[1]); p[2]=f2bf(a[2]); p[3]=f2bf(a[3]);
            p[4]=f2bf(b[0]); p[5]=f2bf(b[1]); p[6]=f2bf(b[2]); p[7]=f2bf(b[3]);
            *reinterpret_cast<s16x8*>((char*)ldsA + srow * 256 + ((sch * 16) ^ ((srow & 7) << 4))) = p;
        }
        __syncthreads();

        // ---- A fragments: one ds_read_b128 each (bank-optimal w/ swizzle) ----
        s16x8 afr[4];
        #pragma unroll
        for (int kt = 0; kt < 4; ++kt)
            afr[kt] = *reinterpret_cast<const s16x8*>(
                (char*)ldsA + lr * 256 + ((kt * 64 + lg * 16) ^ ((lr & 7) << 4)));

        f32x4 acc[4];
        #pragma unroll
        for (int nt = 0; nt < 4; ++nt) acc[nt] = (f32x4){0.f, 0.f, 0.f, 0.f};
        #pragma unroll
        for (int kt = 0; kt < 4; ++kt)
            #pragma unroll
            for (int nt = 0; nt < 4; ++nt)
                acc[nt] = __builtin_amdgcn_mfma_f32_16x16x32_bf16(afr[kt], bfrag[kt][nt], acc[nt], 0, 0, 0);

        // ---- epilogue: acc -> per-wave swizzled LDS slice (bf16, +bias) ----
        // C/D: col = nt*16+lr (within 64), row = lg*4 + rr
        char* Cb = ldsC[w];
        #pragma unroll
        for (int nt = 0; nt < 4; ++nt) {
            const int colb = nt * 32 + lr * 2;
            #pragma unroll
            for (int rr = 0; rr < 4; ++rr) {
                const int row = lg * 4 + rr;
                *(short*)(Cb + row * 128 + (colb ^ ((row & 7) << 4))) = f2bf(acc[nt][rr] + b1v[nt]);
            }
        }
        // wave-private slice; wave-coherent LDS needs only an lgkm drain
        asm volatile("s_waitcnt lgkmcnt(0)" ::: "memory");

        // ---- C slice -> coalesced 16B UV stores (2 chunks per lane) ----
        #pragma unroll
        for (int i = 0; i < 2; ++i) {
            const int idx = l + i * 64;          // 0..127
            const int r2  = idx >> 3;            // 0..15
            const int ch  = idx & 7;             // 0..7  (16B chunks of 128B)
            s16x8 vv = *reinterpret_cast<const s16x8*>(Cb + r2 * 128 + ((ch * 16) ^ ((r2 & 7) << 4)));
            const int grow = R0 + r2;
            if (grow < N_NODES)
                *reinterpret_cast<s16x8*>(&UV[(size_t)grow * 256 + w * 64 + ch * 8]) = vv;
        }
        __syncthreads();   // protect ldsA before next tile's stage
    }
}

// ---------------------------------------------------------------------------
// Edge combine v3: de-serialized gather pipeline.
// launch_bounds(256,4) -> VGPR cap 128 so the 16 named gathers + next-id
// load stay register-resident; sched_barrier(0) pins the whole load cluster
// before any consume (round<=7 ran at VGPR=48: compiler had re-serialized
// the gathers to ~3 in flight, rate-matching the observed 12.4 B/cyc/CU).
// ---------------------------------------------------------------------------
__device__ __forceinline__ float dotrelu8(s16x8 u, s16x8 v, const float* w2v, int off) {
    float a = 0.f;
    #pragma unroll
    for (int j = 0; j < 8; ++j) {
        float s = bf2f(u[j]) + bf2f(v[j]);
        s = s > 0.f ? s : 0.f;
        a += s * w2v[off + j];
    }
    return a;
}

__global__ __launch_bounds__(256, 4) void edge_combine3_kernel(
    const short* __restrict__ UV,
    const int*   __restrict__ src,
    const int*   __restrict__ dst,
    const float* __restrict__ W2,
    const float* __restrict__ b2,
    float* __restrict__ out)
{
    const int t  = threadIdx.x;
    const int w  = t >> 6;
    const int l  = t & 63;
    const int eg = l >> 3;         // edge-in-sub-batch 0..7
    const int dg = l & 7;          // dim group 0..7
    const int dl = dg * 16;        // dim base

    float w2v[16];
    #pragma unroll
    for (int j = 0; j < 16; ++j) w2v[j] = W2[dl + j];
    const float b2v = b2[0];

    const int gw = blockIdx.x * 4 + w;
    const int stride = gridDim.x * 4 * 32;

    int base = gw * 32;
    int jj0 = base + (l & 31); if (jj0 > N_EDGES - 1) jj0 = N_EDGES - 1;
    int ids = (l < 32) ? src[jj0] : dst[jj0];

    for (; base < N_EDGES; base += stride) {
        // broadcast this iteration's 32 edge id-pairs from the coalesced load
        int s0 = __shfl(ids, 0 * 8 + eg, 64), d0 = __shfl(ids, 32 + 0 * 8 + eg, 64);
        int s1 = __shfl(ids, 1 * 8 + eg, 64), d1 = __shfl(ids, 32 + 1 * 8 + eg, 64);
        int s2 = __shfl(ids, 2 * 8 + eg, 64), d2 = __shfl(ids, 32 + 2 * 8 + eg, 64);
        int s3 = __shfl(ids, 3 * 8 + eg, 64), d3 = __shfl(ids, 32 + 3 * 8 + eg, 64);

        // issue ALL 16 gathers as named loads (64 VGPR of payload in flight)
        const s16x8* up0 = (const s16x8*)(UV + (size_t)s0 * 256 + dl);
        const s16x8* vp0 = (const s16x8*)(UV + (size_t)d0 * 256 + 128 + dl);
        const s16x8* up1 = (const s16x8*)(UV + (size_t)s1 * 256 + dl);
        const s16x8* vp1 = (const s16x8*)(UV + (size_t)d1 * 256 + 128 + dl);
        const s16x8* up2 = (const s16x8*)(UV + (size_t)s2 * 256 + dl);
        const s16x8* vp2 = (const s16x8*)(UV + (size_t)d2 * 256 + 128 + dl);
        const s16x8* up3 = (const s16x8*)(UV + (size_t)s3 * 256 + dl);
        const s16x8* vp3 = (const s16x8*)(UV + (size_t)d3 * 256 + 128 + dl);
        s16x8 ua0 = up0[0], ub0 = up0[1], va0 = vp0[0], vb0 = vp0[1];
        s16x8 ua1 = up1[0], ub1 = up1[1], va1 = vp1[0], vb1 = vp1[1];
        s16x8 ua2 = up2[0], ub2 = up2[1], va2 = vp2[0], vb2 = vp2[1];
        s16x8 ua3 = up3[0], ub3 = up3[1], va3 = vp3[0], vb3 = vp3[1];

        // next iteration's ids join the in-flight cluster
        const int nb = base + stride;
        if (nb < N_EDGES) {
            int j2 = nb + (l & 31); if (j2 > N_EDGES - 1) j2 = N_EDGES - 1;
            ids = (l < 32) ? src[j2] : dst[j2];
        }
        __builtin_amdgcn_sched_barrier(0);   // pin load cluster above consumes

        float a0 = dotrelu8(ua0, va0, w2v, 0) + dotrelu8(ub0, vb0, w2v, 8);
        float a1 = dotrelu8(ua1, va1, w2v, 0) + dotrelu8(ub1, vb1, w2v, 8);
        float a2 = dotrelu8(ua2, va2, w2v, 0) + dotrelu8(ub2, vb2, w2v, 8);
        float a3 = dotrelu8(ua3, va3, w2v, 0) + dotrelu8(ub3, vb3, w2v, 8);

        #pragma unroll
        for (int m = 1; m <= 4; m <<= 1) {
            a0 += __shfl_xor(a0, m, 64);
            a1 += __shfl_xor(a1, m, 64);
            a2 += __shfl_xor(a2, m, 64);
            a3 += __shfl_xor(a3, m, 64);
        }

        if (dg == 0) {
            if (base + 0 * 8 + eg < N_EDGES) __builtin_nontemporal_store(a0 + b2v, &out[base + 0 * 8 + eg]);
            if (base + 1 * 8 + eg < N_EDGES) __builtin_nontemporal_store(a1 + b2v, &out[base + 1 * 8 + eg]);
            if (base + 2 * 8 + eg < N_EDGES) __builtin_nontemporal_store(a2 + b2v, &out[base + 2 * 8 + eg]);
            if (base + 3 * 8 + eg < N_EDGES) __builtin_nontemporal_store(a3 + b2v, &out[base + 3 * 8 + eg]);
        }
    }
}

// ---------------------------------------------------------------------------
// v2 fallback (only if ws too small): bf16 h + direct-gather MFMA
// ---------------------------------------------------------------------------
__global__ void conv_h_kernel(const float* __restrict__ h, short* __restrict__ hb) {
    int i = blockIdx.x * blockDim.x + threadIdx.x;
    const int n8 = N_NODES * HF / 8;
    if (i < n8) {
        f32x4 a = ((const f32x4*)h)[i * 2];
        f32x4 b = ((const f32x4*)h)[i * 2 + 1];
        s16x8 p;
        p[0]=f2bf(a[0]); p[1]=f2bf(a[1]); p[2]=f2bf(a[2]); p[3]=f2bf(a[3]);
        p[4]=f2bf(b[0]); p[5]=f2bf(b[1]); p[6]=f2bf(b[2]); p[7]=f2bf(b[3]);
        ((s16x8*)hb)[i] = p;
    }
}

__device__ __forceinline__ void gatherA(const short* __restrict__ hb,
                                        int sid, int did, int lg, s16x8 (&A)[8]) {
    const s16x8* bs = (const s16x8*)(hb + (size_t)sid * HF);
    const s16x8* bd = (const s16x8*)(hb + (size_t)did * HF);
    A[0] = bs[lg];      A[1] = bs[4 + lg];  A[2] = bs[8 + lg];  A[3] = bs[12 + lg];
    A[4] = bd[lg];      A[5] = bd[4 + lg];  A[6] = bd[8 + lg];  A[7] = bd[12 + lg];
}

__device__ __forceinline__ void step_tile_v2(
    int tile, int g,
    const short* __restrict__ hb,
    const int* __restrict__ src, const int* __restrict__ dst,
    s16x8 (&Acur)[8], s16x8 (&Anext)[8],
    int sidg, int didg, int& sid2, int& did2,
    const s16x8 (&bfrag)[8][4],
    const float (&b1v)[4], const float (&w2v)[4], float b2v,
    float* __restrict__ out,
    float (&lds_p)[2][2][MTILE], int pp,
    int t, int r, int c, int lg, int lr, int myrow)
{
    gatherA(hb, sidg, didg, lg, Anext);
    {
        int e = (tile + 2 * g) * MTILE + myrow;
        e = e < N_EDGES ? e : N_EDGES - 1;
        sid2 = src[e]; did2 = dst[e];
    }
    f32x4 acc[4];
    #pragma unroll
    for (int nt = 0; nt < 4; ++nt) acc[nt] = (f32x4){0.f, 0.f, 0.f, 0.f};
    #pragma unroll
    for (int kt = 0; kt < 8; ++kt)
        #pragma unroll
        for (int nt = 0; nt < 4; ++nt)
            acc[nt] = __builtin_amdgcn_mfma_f32_16x16x32_bf16(Acur[kt], bfrag[kt][nt], acc[nt], 0, 0, 0);

    float s0[4];
    #pragma unroll
    for (int rr = 0; rr < 4; ++rr) {
        float a = 0.f;
        #pragma unroll
        for (int nt = 0; nt < 4; ++nt) {
            float v = acc[nt][rr] + b1v[nt];
            v = v > 0.f ? v : 0.f;
            a += v * w2v[nt];
        }
        s0[rr] = a;
    }
    #pragma unroll
    for (int mask = 1; mask <= 8; mask <<= 1)
        #pragma unroll
        for (int rr = 0; rr < 4; ++rr)
            s0[rr] += __shfl_xor(s0[rr], mask, 64);

    if (lr == 0) {
        #pragma unroll
        for (int rr = 0; rr < 4; ++rr)
            lds_p[pp][c][r * 16 + lg * 4 + rr] = s0[rr];
    }
    asm volatile("s_waitcnt lgkmcnt(0)" ::: "memory");
    __builtin_amdgcn_s_barrier();
    asm volatile("" ::: "memory");

    if (t < MTILE) {
        int e = tile * MTILE + t;
        if (e < N_EDGES)
            out[e] = lds_p[pp][0][t] + lds_p[pp][1][t] + b2v;
    }
}

__global__ __launch_bounds__(512, 2) void mlp_edge_score_v2(
    const short* __restrict__ hb,
    const int*   __restrict__ src,
    const int*   __restrict__ dst,
    const float* __restrict__ W1,
    const float* __restrict__ b1,
    const float* __restrict__ W2,
    const float* __restrict__ b2,
    float* __restrict__ out)
{
    __shared__ float lds_p[2][2][MTILE];

    const int t  = threadIdx.x;
    const int w  = t >> 6;
    const int l  = t & 63;
    const int r  = w >> 1;
    const int c  = w & 1;
    const int lg = l >> 4;
    const int lr = l & 15;
    const int myrow = r * 16 + lr;

    s16x8 bfrag[8][4];
    #pragma unroll
    for (int kt = 0; kt < 8; ++kt)
        #pragma unroll
        for (int nt = 0; nt < 4; ++nt) {
            const int n  = c * 64 + nt * 16 + lr;
            const int kb = kt * 32 + lg * 8;
            s16x8 f;
            #pragma unroll
            for (int i = 0; i < 8; ++i) f[i] = f2bf(W1[(size_t)(kb + i) * HF + n]);
            bfrag[kt][nt] = f;
        }
    float b1v[4], w2v[4];
    #pragma unroll
    for (int nt = 0; nt < 4; ++nt) {
        const int n = c * 64 + nt * 16 + lr;
        b1v[nt] = b1[n];
        w2v[nt] = W2[n];
    }
    const float b2v = b2[0];

    const int g = gridDim.x;
    const int tile0 = blockIdx.x;

    s16x8 Aa[8], Ab[8];
    {
        int e = tile0 * MTILE + myrow;
        e = e < N_EDGES ? e : N_EDGES - 1;
        gatherA(hb, src[e], dst[e], lg, Aa);
    }
    int sidA, didA, sidB, didB;
    {
        int e = (tile0 + g) * MTILE + myrow;
        e = e < N_EDGES ? e : N_EDGES - 1;
        sidA = src[e]; didA = dst[e];
    }

    int pp = 0;
    for (int tile = tile0; tile < NTILES; tile += 2 * g) {
        step_tile_v2(tile, g, hb, src, dst, Aa, Ab, sidA, didA, sidB, didB,
                     bfrag, b1v, w2v, b2v, out, lds_p, pp, t, r, c, lg, lr, myrow);
        pp ^= 1;
        if (tile + g < NTILES) {
            step_tile_v2(tile + g, g, hb, src, dst, Ab, Aa, sidB, didB, sidA, didA,
                         bfrag, b1v, w2v, b2v, out, lds_p, pp, t, r, c, lg, lr, myrow);
            pp ^= 1;
        }
    }
}

extern "C" void kernel_launch(void* const* d_in, const int* in_sizes, int n_in,
                              void* d_out, int out_size, void* d_ws, size_t ws_size,
                              hipStream_t stream) {
    const float* h   = (const float*)d_in[0];
    const int*   src = (const int*)  d_in[1];
    const int*   dst = (const int*)  d_in[2];
    const float* W1  = (const float*)d_in[3];
    const float* b1  = (const float*)d_in[4];
    const float* W2  = (const float*)d_in[5];
    const float* b2  = (const float*)d_in[6];
    float* out = (float*)d_out;

    if (ws_size >= WS_NEED) {
        char* ws = (char*)d_ws;
        short* w1f = (short*)ws;
        short* UV  = (short*)(ws + W1F_BYTES);

        conv_w_kernel<<<16, 256, 0, stream>>>(W1, w1f);
        uv_gemm5_kernel<<<1024, 256, 0, stream>>>(h, w1f, b1, UV);
        edge_combine3_kernel<<<1024, 256, 0, stream>>>(UV, src, dst, W2, b2, out);
    } else {
        short* hb = (short*)d_ws;
        const int n8 = N_NODES * HF / 8;
        conv_h_kernel<<<(n8 + 255) / 256, 256, 0, stream>>>(h, hb);
        mlp_edge_score_v2<<<256, 512, 0, stream>>>(hb, src, dst, W1, b1, W2, b2, out);
    }
}